// Round 2
// baseline (794.800 us; speedup 1.0000x reference)
//
#include <hip/hip_runtime.h>
#include <hip/hip_cooperative_groups.h>

namespace cg = cooperative_groups;

// Problem constants (fixed by reference)
#define NN 4096
#define EE 4096
#define BB 3
#define DIN 64
#define HID 32
#define MAXDEG 128          // binomial(4096,0.008): mean 32.8, sd 5.7
#define EPSF 1e-6f

// ---------------------------------------------------------------------------
// Kernel 1: stream H (201 MB, the only HBM-bound op) -> CSR + rowcnt only.
// No global atomics, no scattered CSC writes in the hot loop. Also zeroes
// colcnt (one int per block) so no separate memset dispatch is needed.
// ---------------------------------------------------------------------------
__global__ void build_sparse(const float* __restrict__ H,
                             int* __restrict__ rowcnt,
                             int* __restrict__ colcnt,
                             int* __restrict__ csr) {
    __shared__ int scnt;
    const int bn = blockIdx.x;                    // b*NN + n
    if (threadIdx.x == 0) { scnt = 0; colcnt[bn] = 0; }
    __syncthreads();
    const float4* row = (const float4*)(H + (size_t)bn * EE);
    int* crow = csr + (size_t)bn * MAXDEG;
    for (int k = threadIdx.x; k < EE / 4; k += 256) {
        float4 v = row[k];
        int m = (v.x != 0.f) + (v.y != 0.f) + (v.z != 0.f) + (v.w != 0.f);
        if (m) {                                   // ~3% of threads per iter
            int base = atomicAdd(&scnt, m);        // LDS atomic, cheap
            const int e0 = k * 4;
            if (v.x != 0.f) { if (base < MAXDEG) crow[base] = e0;     base++; }
            if (v.y != 0.f) { if (base < MAXDEG) crow[base] = e0 + 1; base++; }
            if (v.z != 0.f) { if (base < MAXDEG) crow[base] = e0 + 2; base++; }
            if (v.w != 0.f) { if (base < MAXDEG) crow[base] = e0 + 3; base++; }
        }
    }
    __syncthreads();
    if (threadIdx.x == 0) rowcnt[bn] = scnt;       // exact count, even if >MAXDEG
}

// ---------------------------------------------------------------------------
// Shared-memory layout for the fused stages (one struct, ~21.8 KB)
// ---------------------------------------------------------------------------
struct Shm {
    float smem[5120];      // weight staging: stage1 W_init(2048)+Wn0(1024);
                           // stage3/5: Theta(3072)+Wn1/Wp1(1024)+Wp2(1024)
    float su[8][HID];      // per-group 32-float row buffer (bank-conflict-free)
    float sb0[HID];
    float sb1[HID];
    float sw[4];           // softmax(behavior_importance)
};

__device__ __forceinline__ void softmax_w(Shm* S, const float* bimp, int tid) {
    if (tid == 0) {
        float b0 = bimp[0], b1 = bimp[1], b2 = bimp[2];
        float m = fmaxf(b0, fmaxf(b1, b2));
        float e0 = expf(b0 - m), e1 = expf(b1 - m), e2 = expf(b2 - m);
        float s = e0 + e1 + e2;
        S->sw[0] = e0 / s; S->sw[1] = e1 / s; S->sw[2] = e2 / s;
    }
}

// 4-way unrolled gather: 4 independent loads in flight per step
__device__ __forceinline__ float gather_sum(const float* __restrict__ base,
                                            const int* __restrict__ idx,
                                            int iters, int h) {
    float a0 = 0.f, a1 = 0.f, a2 = 0.f, a3 = 0.f;
    int j = 0;
    for (; j + 4 <= iters; j += 4) {
        int n0 = idx[j], n1 = idx[j + 1], n2 = idx[j + 2], n3 = idx[j + 3];
        a0 += base[n0 * HID + h];
        a1 += base[n1 * HID + h];
        a2 += base[n2 * HID + h];
        a3 += base[n3 * HID + h];
    }
    for (; j < iters; j++) a0 += base[idx[j] * HID + h];
    return (a0 + a1) + (a2 + a3);
}

// ---------------------------------------------------------------------------
// Stage 1: x0 = relu(X@Wi+bi); y0 = dv * (x0@Wn0+bn0)  (per-node 32-lane group)
//          + CSC build from CSR (L2-resident, atomics off the HBM path)
// ---------------------------------------------------------------------------
__device__ void stage1(Shm* S, const float* __restrict__ X,
                       const float* __restrict__ Wi, const float* __restrict__ bi,
                       const float* __restrict__ Wn0, const float* __restrict__ bn0,
                       const int* __restrict__ rowcnt, int* __restrict__ colcnt,
                       const int* __restrict__ csr, int* __restrict__ csc,
                       float* __restrict__ ybuf,
                       int g0, int ngroups, int tid, int loc, int h) {
    for (int i = tid; i < DIN * HID; i += 256) S->smem[i] = Wi[i];
    for (int i = tid; i < HID * HID; i += 256) S->smem[2048 + i] = Wn0[i];
    if (tid < HID) { S->sb0[tid] = bi[tid]; S->sb1[tid] = bn0[tid]; }
    __syncthreads();
    for (int n = g0; n < NN; n += ngroups) {
        const float* xr = X + (size_t)n * DIN;
        float acc = S->sb0[h];
#pragma unroll 8
        for (int d = 0; d < DIN; d++) acc = fmaf(xr[d], S->smem[d * HID + h], acc);
        S->su[loc][h] = fmaxf(acc, 0.f);           // wave-synchronous (32-lane group)
        float a = S->sb1[h];
#pragma unroll
        for (int hh = 0; hh < HID; hh++)
            a = fmaf(S->su[loc][hh], S->smem[2048 + hh * HID + h], a);
#pragma unroll
        for (int b = 0; b < BB; b++) {
            float c = (float)rowcnt[b * NN + n];
            ybuf[((size_t)b * NN + n) * HID + h] = a * rsqrtf(fmaxf(c, EPSF));
        }
    }
    // CSC from CSR: one 32-lane group per row, global atomics hit L2 only
    for (int r = g0; r < BB * NN; r += ngroups) {
        int cnt = min(rowcnt[r], MAXDEG);
        int cbase = (r >> 12) << 12;               // b*EE
        int n = r & (NN - 1);
        for (int j = h; j < cnt; j += 32) {
            int e = csr[(size_t)r * MAXDEG + j];
            int ce = cbase + e;
            int slot = atomicAdd(&colcnt[ce], 1);
            if (slot < MAXDEG) csc[(size_t)ce * MAXDEG + slot] = n;
        }
    }
}

// ---------------------------------------------------------------------------
// Z stage: z[b,e,:] = de * sum_{n in csc(b,e)} y[b,n,:]
// ---------------------------------------------------------------------------
__device__ void zstage(const int* __restrict__ colcnt, const int* __restrict__ csc,
                       const float* __restrict__ ybuf, float* __restrict__ zbuf,
                       int g0, int ngroups, int h) {
    for (int be = g0; be < BB * EE; be += ngroups) {
        int cnt = colcnt[be];
        int iters = min(cnt, MAXDEG);
        const int* idx = csc + (size_t)be * MAXDEG;
        const float* yb = ybuf + (size_t)(be >> 12) * NN * HID;
        float s = gather_sum(yb, idx, iters, h);
        zbuf[(size_t)be * HID + h] = s * (1.0f / fmaxf((float)cnt, EPSF));
    }
}

// ---------------------------------------------------------------------------
// U core: x_new[n,h] = relu( sum_b w[b] * ( (dv*H z)[b,n,:] @ Theta_b )[h] )
// ---------------------------------------------------------------------------
__device__ __forceinline__ float ucore(Shm* S, const float* __restrict__ zbuf,
                                       const int* __restrict__ rowcnt,
                                       const int* __restrict__ csr,
                                       int n, int loc, int h) {
    float accx = 0.f;
#pragma unroll
    for (int b = 0; b < BB; b++) {
        int bn = b * NN + n;
        int cnt = rowcnt[bn];
        int iters = min(cnt, MAXDEG);
        const int* idx = csr + (size_t)bn * MAXDEG;
        const float* zb = zbuf + (size_t)b * EE * HID;
        float u = gather_sum(zb, idx, iters, h) * rsqrtf(fmaxf((float)cnt, EPSF));
        S->su[loc][h] = u;                          // wave-synchronous
        float msg = 0.f;
#pragma unroll
        for (int hh = 0; hh < HID; hh++)
            msg = fmaf(S->su[loc][hh], S->smem[b * (HID * HID) + hh * HID + h], msg);
        accx = fmaf(S->sw[b], msg, accx);
    }
    return fmaxf(accx, 0.f);
}

// Stage 3: u0 -> x1 -> y1 (x1 never hits global memory)
__device__ void stage3(Shm* S, const float* __restrict__ Theta,
                       const float* __restrict__ Wn1, const float* __restrict__ bn1,
                       const float* __restrict__ bimp,
                       const float* __restrict__ zbuf, const int* __restrict__ rowcnt,
                       const int* __restrict__ csr, float* __restrict__ ybuf,
                       int g0, int ngroups, int tid, int loc, int h) {
    __syncthreads();
    for (int i = tid; i < BB * HID * HID; i += 256) S->smem[i] = Theta[i];
    for (int i = tid; i < HID * HID; i += 256) S->smem[3072 + i] = Wn1[i];
    if (tid < HID) S->sb1[tid] = bn1[tid];
    softmax_w(S, bimp, tid);
    __syncthreads();
    for (int n = g0; n < NN; n += ngroups) {
        float xn = ucore(S, zbuf, rowcnt, csr, n, loc, h);
        S->su[loc][h] = xn;
        float a = S->sb1[h];
#pragma unroll
        for (int hh = 0; hh < HID; hh++)
            a = fmaf(S->su[loc][hh], S->smem[3072 + hh * HID + h], a);
#pragma unroll
        for (int b = 0; b < BB; b++) {
            float c = (float)rowcnt[b * NN + n];
            ybuf[((size_t)b * NN + n) * HID + h] = a * rsqrtf(fmaxf(c, EPSF));
        }
    }
}

// Stage 5: u1 -> x2 -> projection -> out
__device__ void stage5(Shm* S, const float* __restrict__ Theta,
                       const float* __restrict__ Wp1, const float* __restrict__ bp1,
                       const float* __restrict__ Wp2, const float* __restrict__ bp2,
                       const float* __restrict__ bimp,
                       const float* __restrict__ zbuf, const int* __restrict__ rowcnt,
                       const int* __restrict__ csr, float* __restrict__ out,
                       int g0, int ngroups, int tid, int loc, int h) {
    __syncthreads();
    for (int i = tid; i < BB * HID * HID; i += 256) S->smem[i] = Theta[i];
    for (int i = tid; i < HID * HID; i += 256) {
        S->smem[3072 + i] = Wp1[i];
        S->smem[4096 + i] = Wp2[i];
    }
    if (tid < HID) { S->sb1[tid] = bp1[tid]; S->sb0[tid] = bp2[tid]; }
    softmax_w(S, bimp, tid);
    __syncthreads();
    for (int n = g0; n < NN; n += ngroups) {
        float xn = ucore(S, zbuf, rowcnt, csr, n, loc, h);
        S->su[loc][h] = xn;
        float p = S->sb1[h];
#pragma unroll
        for (int hh = 0; hh < HID; hh++)
            p = fmaf(S->su[loc][hh], S->smem[3072 + hh * HID + h], p);
        p = fmaxf(p, 0.f);
        S->su[loc][h] = p;                          // in-order within wave: safe
        float o = S->sb0[h];
#pragma unroll
        for (int hh = 0; hh < HID; hh++)
            o = fmaf(S->su[loc][hh], S->smem[4096 + hh * HID + h], o);
        out[(size_t)n * HID + h] = o;
    }
}

// ---------------------------------------------------------------------------
// Fused cooperative kernel: everything after build_sparse in ONE launch.
// Grid-stride work loops -> any co-resident grid size works.
// ---------------------------------------------------------------------------
__global__ __launch_bounds__(256, 4) void mega(
        const float* X, const float* Wi, const float* bi,
        const float* Wn, const float* bn,
        const float* Theta, const float* bimp,
        const float* Wp1, const float* bp1, const float* Wp2, const float* bp2,
        const int* rowcnt, int* colcnt, const int* csr, int* csc,
        float* ybuf, float* zbuf, float* out) {
    __shared__ Shm S;
    cg::grid_group grid = cg::this_grid();
    const int tid = threadIdx.x, loc = tid >> 5, h = tid & 31;
    const int g0 = blockIdx.x * 8 + loc;
    const int ngroups = gridDim.x * 8;
    stage1(&S, X, Wi, bi, Wn, bn, rowcnt, colcnt, csr, csc, ybuf, g0, ngroups, tid, loc, h);
    grid.sync();
    zstage(colcnt, csc, ybuf, zbuf, g0, ngroups, h);
    grid.sync();
    stage3(&S, Theta, Wn + HID * HID, bn + HID, bimp, zbuf, rowcnt, csr, ybuf, g0, ngroups, tid, loc, h);
    grid.sync();
    zstage(colcnt, csc, ybuf, zbuf, g0, ngroups, h);
    grid.sync();
    stage5(&S, Theta, Wp1, bp1, Wp2, bp2, bimp, zbuf, rowcnt, csr, out, g0, ngroups, tid, loc, h);
}

// ---------------------------------------------------------------------------
// Fallback (non-cooperative) stage kernels, same device bodies
// ---------------------------------------------------------------------------
__global__ __launch_bounds__(256, 4) void k_stage1(
        const float* X, const float* Wi, const float* bi,
        const float* Wn, const float* bn,
        const int* rowcnt, int* colcnt, const int* csr, int* csc, float* ybuf) {
    __shared__ Shm S;
    const int tid = threadIdx.x, loc = tid >> 5, h = tid & 31;
    stage1(&S, X, Wi, bi, Wn, bn, rowcnt, colcnt, csr, csc, ybuf,
           blockIdx.x * 8 + loc, gridDim.x * 8, tid, loc, h);
}
__global__ __launch_bounds__(256, 4) void k_z(
        const int* colcnt, const int* csc, const float* ybuf, float* zbuf) {
    const int tid = threadIdx.x, loc = tid >> 5, h = tid & 31;
    zstage(colcnt, csc, ybuf, zbuf, blockIdx.x * 8 + loc, gridDim.x * 8, h);
}
__global__ __launch_bounds__(256, 4) void k_stage3(
        const float* Theta, const float* Wn1, const float* bn1, const float* bimp,
        const float* zbuf, const int* rowcnt, const int* csr, float* ybuf) {
    __shared__ Shm S;
    const int tid = threadIdx.x, loc = tid >> 5, h = tid & 31;
    stage3(&S, Theta, Wn1, bn1, bimp, zbuf, rowcnt, csr, ybuf,
           blockIdx.x * 8 + loc, gridDim.x * 8, tid, loc, h);
}
__global__ __launch_bounds__(256, 4) void k_stage5(
        const float* Theta, const float* Wp1, const float* bp1,
        const float* Wp2, const float* bp2, const float* bimp,
        const float* zbuf, const int* rowcnt, const int* csr, float* out) {
    __shared__ Shm S;
    const int tid = threadIdx.x, loc = tid >> 5, h = tid & 31;
    stage5(&S, Theta, Wp1, bp1, Wp2, bp2, bimp, zbuf, rowcnt, csr, out,
           blockIdx.x * 8 + loc, gridDim.x * 8, tid, loc, h);
}

// ---------------------------------------------------------------------------
extern "C" void kernel_launch(void* const* d_in, const int* in_sizes, int n_in,
                              void* d_out, int out_size, void* d_ws, size_t ws_size,
                              hipStream_t stream) {
    const float* X      = (const float*)d_in[0];
    const float* H      = (const float*)d_in[1];
    const float* W_init = (const float*)d_in[2];
    const float* b_init = (const float*)d_in[3];
    const float* W_node = (const float*)d_in[4];   // [2, HID, HID]
    const float* b_node = (const float*)d_in[5];   // [2, HID]
    const float* Theta  = (const float*)d_in[6];   // [BB, HID, HID]
    const float* bimp   = (const float*)d_in[7];   // [BB]
    const float* Wp1    = (const float*)d_in[8];
    const float* bp1    = (const float*)d_in[9];
    const float* Wp2    = (const float*)d_in[10];
    const float* bp2    = (const float*)d_in[11];
    float* out = (float*)d_out;
    (void)in_sizes; (void)n_in; (void)out_size; (void)ws_size;

    char* ws = (char*)d_ws;
    size_t off = 0;
    auto alloc = [&](size_t bytes) { void* p = ws + off; off += (bytes + 255) & ~(size_t)255; return p; };
    int*   rowcnt = (int*)alloc((size_t)BB * NN * 4);
    int*   colcnt = (int*)alloc((size_t)BB * EE * 4);
    int*   csr    = (int*)alloc((size_t)BB * NN * MAXDEG * 4);
    int*   csc    = (int*)alloc((size_t)BB * EE * MAXDEG * 4);
    float* ybuf   = (float*)alloc((size_t)BB * NN * HID * 4);
    float* zbuf   = (float*)alloc((size_t)BB * EE * HID * 4);

    build_sparse<<<BB * NN, 256, 0, stream>>>(H, rowcnt, colcnt, csr);

    int occ = 0;
    if (hipOccupancyMaxActiveBlocksPerMultiprocessor(&occ, mega, 256, 0) != hipSuccess || occ < 1)
        occ = 2;                                   // conservative fallback
    if (occ > 7) occ = 7;                          // LDS cap: 7*21.8KB < 160KB
    int nblk = occ * 256;                          // 256 CUs on MI355X
    if (nblk > 1536) nblk = 1536;                  // >= work units beyond this

    void* args[] = {
        (void*)&X, (void*)&W_init, (void*)&b_init, (void*)&W_node, (void*)&b_node,
        (void*)&Theta, (void*)&bimp, (void*)&Wp1, (void*)&bp1, (void*)&Wp2, (void*)&bp2,
        (void*)&rowcnt, (void*)&colcnt, (void*)&csr, (void*)&csc,
        (void*)&ybuf, (void*)&zbuf, (void*)&out,
    };
    hipError_t ce = hipLaunchCooperativeKernel(mega, dim3(nblk), dim3(256), args, 0, stream);
    if (ce != hipSuccess) {
        // non-cooperative fallback: 5 kernels, same device code
        k_stage1<<<1536, 256, 0, stream>>>(X, W_init, b_init, W_node, b_node,
                                           rowcnt, colcnt, csr, csc, ybuf);
        k_z<<<1536, 256, 0, stream>>>(colcnt, csc, ybuf, zbuf);
        k_stage3<<<1536, 256, 0, stream>>>(Theta, W_node + HID * HID, b_node + HID, bimp,
                                           zbuf, rowcnt, csr, ybuf);
        k_z<<<1536, 256, 0, stream>>>(colcnt, csc, ybuf, zbuf);
        k_stage5<<<1536, 256, 0, stream>>>(Theta, Wp1, bp1, Wp2, bp2, bimp,
                                           zbuf, rowcnt, csr, out);
    }
}

// Round 3
// 448.619 us; speedup vs baseline: 1.7717x; 1.7717x over previous
//
#include <hip/hip_runtime.h>

// Problem constants (fixed by reference)
#define NN 4096
#define EE 4096
#define BB 3
#define DIN 64
#define HID 32
#define MAXDEG 128          // binomial(4096,0.008): mean 32.8, sd 5.7; max ~59
#define EPSF 1e-6f

// ---------------------------------------------------------------------------
// K0: zero the accumulator region (colcnt + z0acc + z1acc, contiguous).
// Harness poisons d_ws with 0xAA before every call, so this must run each time.
// ---------------------------------------------------------------------------
__global__ void k_zero(int4* __restrict__ p, int n4) {
    int i = blockIdx.x * 256 + threadIdx.x;
    const int stride = gridDim.x * 256;
    const int4 z = {0, 0, 0, 0};
    for (; i < n4; i += stride) p[i] = z;
}

// ---------------------------------------------------------------------------
// K1: xw0[n,:] = relu(X @ W_init + b_init) @ W_node0 + b_node0   (no dv yet)
// ---------------------------------------------------------------------------
__global__ __launch_bounds__(256) void k_xw0(
        const float* __restrict__ X,
        const float* __restrict__ Wi, const float* __restrict__ bi,
        const float* __restrict__ Wn0, const float* __restrict__ bn0,
        float* __restrict__ xw0) {
    __shared__ float sWi[DIN * HID];
    __shared__ float sWn[HID * HID];
    __shared__ float sb0[HID], sb1[HID];
    __shared__ float su[8][HID];
    const int tid = threadIdx.x;
    for (int i = tid; i < DIN * HID; i += 256) sWi[i] = Wi[i];
    for (int i = tid; i < HID * HID; i += 256) sWn[i] = Wn0[i];
    if (tid < HID) { sb0[tid] = bi[tid]; sb1[tid] = bn0[tid]; }
    __syncthreads();
    const int h = tid & 31, loc = tid >> 5;
    const int n = blockIdx.x * 8 + loc;
    const float* xr = X + (size_t)n * DIN;
    float acc = sb0[h];
#pragma unroll 8
    for (int d = 0; d < DIN; d++) acc = fmaf(xr[d], sWi[d * HID + h], acc);
    su[loc][h] = fmaxf(acc, 0.f);                  // wave-internal, no barrier
    float a = sb1[h];
#pragma unroll
    for (int hh = 0; hh < HID; hh++) a = fmaf(su[loc][hh], sWn[hh * HID + h], a);
    xw0[n * HID + h] = a;
}

// ---------------------------------------------------------------------------
// K2: ONE streaming pass over H (201 MB). Per (b,n) row-block:
//   - edge list -> LDS, exact count -> rowcnt, list -> csr
//   - colcnt[b,e] += 1            (fire-and-forget int atomic -> de later)
//   - z0acc[b,e,:] += xw0[n,:]*dv (fire-and-forget f32 atomics = layer-0 H^T y)
// No atomic returns on the global path; no CSC ever built.
// ---------------------------------------------------------------------------
__global__ __launch_bounds__(256) void k_scan(
        const float* __restrict__ H, const float* __restrict__ xw0,
        int* __restrict__ rowcnt, int* __restrict__ csr,
        int* __restrict__ colcnt, float* __restrict__ z0acc) {
    __shared__ int el[MAXDEG];
    __shared__ int scnt;
    __shared__ float sy[HID];
    const int bn = blockIdx.x, b = bn >> 12, n = bn & (NN - 1);
    const int tid = threadIdx.x;
    if (tid == 0) scnt = 0;
    if (tid < HID) sy[tid] = xw0[n * HID + tid];
    __syncthreads();
    const float4* row = (const float4*)(H + (size_t)bn * EE);
    int* ccb = colcnt + (b << 12);
    for (int k = tid; k < EE / 4; k += 256) {
        float4 v = row[k];
        int m = (v.x != 0.f) + (v.y != 0.f) + (v.z != 0.f) + (v.w != 0.f);
        if (m) {                                   // ~3% of threads per iter
            int base = atomicAdd(&scnt, m);        // LDS atomic
            const int e0 = k * 4;
            if (v.x != 0.f) { if (base < MAXDEG) el[base] = e0;     atomicAdd(&ccb[e0], 1);     base++; }
            if (v.y != 0.f) { if (base < MAXDEG) el[base] = e0 + 1; atomicAdd(&ccb[e0 + 1], 1); base++; }
            if (v.z != 0.f) { if (base < MAXDEG) el[base] = e0 + 2; atomicAdd(&ccb[e0 + 2], 1); base++; }
            if (v.w != 0.f) { if (base < MAXDEG) el[base] = e0 + 3; atomicAdd(&ccb[e0 + 3], 1); base++; }
        }
    }
    __syncthreads();
    const int cnt = scnt;
    if (tid == 0) rowcnt[bn] = cnt;                // exact count (dv/de exactness)
    const int m = min(cnt, MAXDEG);
    for (int j = tid; j < m; j += 256) csr[(size_t)bn * MAXDEG + j] = el[j];
    const float dvinv = rsqrtf(fmaxf((float)cnt, EPSF));
    const int h = tid & 31, g = tid >> 5;
    const float yv = sy[h] * dvinv;
    float* zb = z0acc + ((size_t)(b << 12)) * HID;
    for (int j = g; j < m; j += 8)
        atomicAdd(&zb[el[j] * HID + h], yv);       // no return -> pipelined
}

// ---------------------------------------------------------------------------
// Gather core: u_raw[h] = sum_{e in csr row} zacc[e,h] / max(colcnt[e], eps)
// 4 independent accumulator chains to keep gathers in flight.
// ---------------------------------------------------------------------------
__device__ __forceinline__ float gather_u(const float* __restrict__ zb,
                                          const int* __restrict__ cc,
                                          const int* __restrict__ idx,
                                          int iters, int h) {
    float a0 = 0.f, a1 = 0.f, a2 = 0.f, a3 = 0.f;
    int j = 0;
    for (; j + 4 <= iters; j += 4) {
        int e0 = idx[j], e1 = idx[j + 1], e2 = idx[j + 2], e3 = idx[j + 3];
        float r0 = zb[e0 * HID + h], r1 = zb[e1 * HID + h];
        float r2 = zb[e2 * HID + h], r3 = zb[e3 * HID + h];
        float c0 = (float)cc[e0], c1 = (float)cc[e1];
        float c2 = (float)cc[e2], c3 = (float)cc[e3];
        a0 += r0 / fmaxf(c0, EPSF);
        a1 += r1 / fmaxf(c1, EPSF);
        a2 += r2 / fmaxf(c2, EPSF);
        a3 += r3 / fmaxf(c3, EPSF);
    }
    for (; j < iters; j++) {
        int e = idx[j];
        a0 += zb[e * HID + h] / fmaxf((float)cc[e], EPSF);
    }
    return (a0 + a1) + (a2 + a3);
}

__device__ __forceinline__ void softmax3(const float* __restrict__ bimp, float* sw) {
    float b0 = bimp[0], b1 = bimp[1], b2 = bimp[2];
    float m = fmaxf(b0, fmaxf(b1, b2));
    float e0 = expf(b0 - m), e1 = expf(b1 - m), e2 = expf(b2 - m);
    float s = e0 + e1 + e2;
    sw[0] = e0 / s; sw[1] = e1 / s; sw[2] = e2 / s;
}

// ---------------------------------------------------------------------------
// K3: layer-0 u/Theta/combine -> x1; then xw1 = x1@Wn1+bn1, and scatter
// z1acc[b,e,:] += xw1[n,:]*dv[b,n] over csr (layer-1 H^T y fused in).
// ---------------------------------------------------------------------------
__global__ __launch_bounds__(256) void k_layer(
        const float* __restrict__ zacc, const int* __restrict__ colcnt,
        const int* __restrict__ rowcnt, const int* __restrict__ csr,
        const float* __restrict__ Theta, const float* __restrict__ bimp,
        const float* __restrict__ Wn1, const float* __restrict__ bn1,
        float* __restrict__ z1acc) {
    __shared__ float sTh[BB * HID * HID];
    __shared__ float sW[HID * HID];
    __shared__ float sb[HID];
    __shared__ float su[8][HID];
    __shared__ float sw[4];
    const int tid = threadIdx.x;
    for (int i = tid; i < BB * HID * HID; i += 256) sTh[i] = Theta[i];
    for (int i = tid; i < HID * HID; i += 256) sW[i] = Wn1[i];
    if (tid < HID) sb[tid] = bn1[tid];
    if (tid == 0) softmax3(bimp, sw);
    __syncthreads();
    const int h = tid & 31, loc = tid >> 5;
    const int n = blockIdx.x * 8 + loc;
    float accx = 0.f;
#pragma unroll
    for (int b = 0; b < BB; b++) {
        const int bn = (b << 12) + n;
        const int cnt = rowcnt[bn];
        const int iters = min(cnt, MAXDEG);
        const int* idx = csr + (size_t)bn * MAXDEG;
        const float* zb = zacc + ((size_t)(b << 12)) * HID;
        const int* cc = colcnt + (b << 12);
        float u = gather_u(zb, cc, idx, iters, h) * rsqrtf(fmaxf((float)cnt, EPSF));
        su[loc][h] = u;                             // wave-internal
        float msg = 0.f;
#pragma unroll
        for (int hh = 0; hh < HID; hh++)
            msg = fmaf(su[loc][hh], sTh[b * (HID * HID) + hh * HID + h], msg);
        accx = fmaf(sw[b], msg, accx);
    }
    su[loc][h] = fmaxf(accx, 0.f);                  // x1
    float a = sb[h];
#pragma unroll
    for (int hh = 0; hh < HID; hh++) a = fmaf(su[loc][hh], sW[hh * HID + h], a);
    // scatter xw1*dv into z1acc over each behavior's csr row
#pragma unroll
    for (int b = 0; b < BB; b++) {
        const int bn = (b << 12) + n;
        const int cnt = rowcnt[bn];
        const int iters = min(cnt, MAXDEG);
        const float yv = a * rsqrtf(fmaxf((float)cnt, EPSF));
        const int* idx = csr + (size_t)bn * MAXDEG;
        float* zb = z1acc + ((size_t)(b << 12)) * HID;
        for (int j = 0; j < iters; j++)
            atomicAdd(&zb[idx[j] * HID + h], yv);   // no return -> pipelined
    }
}

// ---------------------------------------------------------------------------
// K4: layer-1 u/Theta/combine -> x2; projection -> out
// ---------------------------------------------------------------------------
__global__ __launch_bounds__(256) void k_final(
        const float* __restrict__ zacc, const int* __restrict__ colcnt,
        const int* __restrict__ rowcnt, const int* __restrict__ csr,
        const float* __restrict__ Theta, const float* __restrict__ bimp,
        const float* __restrict__ Wp1, const float* __restrict__ bp1,
        const float* __restrict__ Wp2, const float* __restrict__ bp2,
        float* __restrict__ out) {
    __shared__ float sTh[BB * HID * HID];
    __shared__ float sW1[HID * HID], sW2[HID * HID];
    __shared__ float sb1[HID], sb2[HID];
    __shared__ float su[8][HID];
    __shared__ float sw[4];
    const int tid = threadIdx.x;
    for (int i = tid; i < BB * HID * HID; i += 256) sTh[i] = Theta[i];
    for (int i = tid; i < HID * HID; i += 256) { sW1[i] = Wp1[i]; sW2[i] = Wp2[i]; }
    if (tid < HID) { sb1[tid] = bp1[tid]; sb2[tid] = bp2[tid]; }
    if (tid == 0) softmax3(bimp, sw);
    __syncthreads();
    const int h = tid & 31, loc = tid >> 5;
    const int n = blockIdx.x * 8 + loc;
    float accx = 0.f;
#pragma unroll
    for (int b = 0; b < BB; b++) {
        const int bn = (b << 12) + n;
        const int cnt = rowcnt[bn];
        const int iters = min(cnt, MAXDEG);
        const int* idx = csr + (size_t)bn * MAXDEG;
        const float* zb = zacc + ((size_t)(b << 12)) * HID;
        const int* cc = colcnt + (b << 12);
        float u = gather_u(zb, cc, idx, iters, h) * rsqrtf(fmaxf((float)cnt, EPSF));
        su[loc][h] = u;
        float msg = 0.f;
#pragma unroll
        for (int hh = 0; hh < HID; hh++)
            msg = fmaf(su[loc][hh], sTh[b * (HID * HID) + hh * HID + h], msg);
        accx = fmaf(sw[b], msg, accx);
    }
    su[loc][h] = fmaxf(accx, 0.f);                  // x2
    float p = sb1[h];
#pragma unroll
    for (int hh = 0; hh < HID; hh++) p = fmaf(su[loc][hh], sW1[hh * HID + h], p);
    su[loc][h] = fmaxf(p, 0.f);                     // program-order within wave
    float o = sb2[h];
#pragma unroll
    for (int hh = 0; hh < HID; hh++) o = fmaf(su[loc][hh], sW2[hh * HID + h], o);
    out[(size_t)n * HID + h] = o;
}

// ---------------------------------------------------------------------------
extern "C" void kernel_launch(void* const* d_in, const int* in_sizes, int n_in,
                              void* d_out, int out_size, void* d_ws, size_t ws_size,
                              hipStream_t stream) {
    const float* X      = (const float*)d_in[0];
    const float* H      = (const float*)d_in[1];
    const float* W_init = (const float*)d_in[2];
    const float* b_init = (const float*)d_in[3];
    const float* W_node = (const float*)d_in[4];   // [2, HID, HID]
    const float* b_node = (const float*)d_in[5];   // [2, HID]
    const float* Theta  = (const float*)d_in[6];   // [BB, HID, HID]
    const float* bimp   = (const float*)d_in[7];   // [BB]
    const float* Wp1    = (const float*)d_in[8];
    const float* bp1    = (const float*)d_in[9];
    const float* Wp2    = (const float*)d_in[10];
    const float* bp2    = (const float*)d_in[11];
    float* out = (float*)d_out;
    (void)in_sizes; (void)n_in; (void)out_size; (void)ws_size;

    char* ws = (char*)d_ws;
    size_t off = 0;
    auto alloc = [&](size_t bytes) { void* p = ws + off; off += (bytes + 255) & ~(size_t)255; return p; };
    int*   rowcnt = (int*)alloc((size_t)BB * NN * 4);
    int*   csr    = (int*)alloc((size_t)BB * NN * MAXDEG * 4);
    float* xw0    = (float*)alloc((size_t)NN * HID * 4);
    // contiguous zero region: colcnt | z0acc | z1acc
    int*   colcnt = (int*)alloc((size_t)BB * EE * 4);
    float* z0acc  = (float*)alloc((size_t)BB * EE * HID * 4);
    float* z1acc  = (float*)alloc((size_t)BB * EE * HID * 4);

    const int n_zero_i4 = (BB * EE + 2 * BB * EE * HID) / 4;   // 199680 int4
    k_zero<<<512, 256, 0, stream>>>((int4*)colcnt, n_zero_i4);
    k_xw0<<<NN / 8, 256, 0, stream>>>(X, W_init, b_init, W_node, b_node, xw0);
    k_scan<<<BB * NN, 256, 0, stream>>>(H, xw0, rowcnt, csr, colcnt, z0acc);
    k_layer<<<NN / 8, 256, 0, stream>>>(z0acc, colcnt, rowcnt, csr,
                                        Theta, bimp, W_node + HID * HID, b_node + HID, z1acc);
    k_final<<<NN / 8, 256, 0, stream>>>(z1acc, colcnt, rowcnt, csr,
                                        Theta, bimp, Wp1, bp1, Wp2, bp2, out);
}

// Round 4
// 391.380 us; speedup vs baseline: 2.0308x; 1.1462x over previous
//
#include <hip/hip_runtime.h>

// Problem constants (fixed by reference)
#define NN 4096
#define EE 4096
#define BB 3
#define DIN 64
#define HID 32
#define MAXDEG 128          // binomial(4096,0.008): mean 32.8, sd 5.7; max ~59
#define EPSF 1e-6f

// ---------------------------------------------------------------------------
// K1: ONE pure streaming pass over H (201 MB) -> CSR + rowcnt. NO global
// atomics anywhere in this kernel (R2 measured this exact structure at
// ~30 us = ~6.7 TB/s; R3's atomic-polluted variant collapsed to latency-
// bound). Also zeroes colcnt (one int per block) for the later CSC build.
// ---------------------------------------------------------------------------
__global__ void build_sparse(const float* __restrict__ H,
                             int* __restrict__ rowcnt,
                             int* __restrict__ colcnt,
                             int* __restrict__ csr) {
    __shared__ int scnt;
    const int bn = blockIdx.x;                    // b*NN + n
    if (threadIdx.x == 0) { scnt = 0; colcnt[bn] = 0; }
    __syncthreads();
    const float4* row = (const float4*)(H + (size_t)bn * EE);
    int* crow = csr + (size_t)bn * MAXDEG;
    for (int k = threadIdx.x; k < EE / 4; k += 256) {
        float4 v = row[k];
        int m = (v.x != 0.f) + (v.y != 0.f) + (v.z != 0.f) + (v.w != 0.f);
        if (m) {                                   // ~3% of threads per iter
            int base = atomicAdd(&scnt, m);        // LDS atomic only
            const int e0 = k * 4;
            if (v.x != 0.f) { if (base < MAXDEG) crow[base] = e0;     base++; }
            if (v.y != 0.f) { if (base < MAXDEG) crow[base] = e0 + 1; base++; }
            if (v.z != 0.f) { if (base < MAXDEG) crow[base] = e0 + 2; base++; }
            if (v.w != 0.f) { if (base < MAXDEG) crow[base] = e0 + 3; base++; }
        }
    }
    __syncthreads();
    if (threadIdx.x == 0) rowcnt[bn] = scnt;       // exact count (dv exactness)
}

// ---------------------------------------------------------------------------
// K2: CSC from CSR — L2-resident, off the HBM path. ~403K atomics total.
// One 32-lane group per (b,n) row.
// ---------------------------------------------------------------------------
__global__ __launch_bounds__(256) void k_csc(
        const int* __restrict__ rowcnt, const int* __restrict__ csr,
        int* __restrict__ colcnt, int* __restrict__ csc) {
    const int tid = threadIdx.x, lane = tid & 31, g = tid >> 5;
    const int r = blockIdx.x * 8 + g;              // row index bn
    const int b = r >> 12, n = r & (NN - 1);
    const int cnt = min(rowcnt[r], MAXDEG);
    const int* row = csr + (size_t)r * MAXDEG;
    int* cc = colcnt + (b << 12);
    for (int j = lane; j < cnt; j += 32) {
        const int e = row[j];
        const int slot = atomicAdd(&cc[e], 1);
        if (slot < MAXDEG) csc[((size_t)(b << 12) + e) * MAXDEG + slot] = n;
    }
}

// ---------------------------------------------------------------------------
// K3: y[b,n,:] = dv[b,n] * (relu(X@Wi+bi) @ Wn0 + bn0)
// ---------------------------------------------------------------------------
__global__ __launch_bounds__(256) void k_xw0(
        const float* __restrict__ X,
        const float* __restrict__ Wi, const float* __restrict__ bi,
        const float* __restrict__ Wn0, const float* __restrict__ bn0,
        const int* __restrict__ rowcnt, float* __restrict__ ybuf) {
    __shared__ float sWi[DIN * HID];
    __shared__ float sWn[HID * HID];
    __shared__ float sb0[HID], sb1[HID];
    __shared__ float su[8][HID];
    const int tid = threadIdx.x;
    for (int i = tid; i < DIN * HID; i += 256) sWi[i] = Wi[i];
    for (int i = tid; i < HID * HID; i += 256) sWn[i] = Wn0[i];
    if (tid < HID) { sb0[tid] = bi[tid]; sb1[tid] = bn0[tid]; }
    __syncthreads();
    const int h = tid & 31, loc = tid >> 5;
    const int n = blockIdx.x * 8 + loc;
    const float* xr = X + (size_t)n * DIN;
    float acc = sb0[h];
#pragma unroll 8
    for (int d = 0; d < DIN; d++) acc = fmaf(xr[d], sWi[d * HID + h], acc);
    su[loc][h] = fmaxf(acc, 0.f);                  // wave-internal, no barrier
    float a = sb1[h];
#pragma unroll
    for (int hh = 0; hh < HID; hh++) a = fmaf(su[loc][hh], sWn[hh * HID + h], a);
#pragma unroll
    for (int b = 0; b < BB; b++) {
        const float c = (float)rowcnt[(b << 12) + n];
        ybuf[((size_t)(b << 12) + n) * HID + h] = a * rsqrtf(fmaxf(c, EPSF));
    }
}

// ---------------------------------------------------------------------------
// Pure gather: sum rows[idx[j]][h], 4 independent chains in flight
// ---------------------------------------------------------------------------
__device__ __forceinline__ float gather_sum(const float* __restrict__ base,
                                            const int* __restrict__ idx,
                                            int iters, int h) {
    float a0 = 0.f, a1 = 0.f, a2 = 0.f, a3 = 0.f;
    int j = 0;
    for (; j + 4 <= iters; j += 4) {
        int n0 = idx[j], n1 = idx[j + 1], n2 = idx[j + 2], n3 = idx[j + 3];
        a0 += base[n0 * HID + h];
        a1 += base[n1 * HID + h];
        a2 += base[n2 * HID + h];
        a3 += base[n3 * HID + h];
    }
    for (; j < iters; j++) a0 += base[idx[j] * HID + h];
    return (a0 + a1) + (a2 + a3);
}

__device__ __forceinline__ void softmax3(const float* __restrict__ bimp, float* sw) {
    float b0 = bimp[0], b1 = bimp[1], b2 = bimp[2];
    float m = fmaxf(b0, fmaxf(b1, b2));
    float e0 = expf(b0 - m), e1 = expf(b1 - m), e2 = expf(b2 - m);
    float s = e0 + e1 + e2;
    sw[0] = e0 / s; sw[1] = e1 / s; sw[2] = e2 / s;
}

// ---------------------------------------------------------------------------
// K4 (x2): z[b,e,:] = de[b,e] * sum_{n in csc(b,e)} y[b,n,:]  (pure gather)
// ---------------------------------------------------------------------------
__global__ __launch_bounds__(256) void k_z(
        const int* __restrict__ colcnt, const int* __restrict__ csc,
        const float* __restrict__ ybuf, float* __restrict__ zbuf) {
    const int tid = threadIdx.x, h = tid & 31, g = tid >> 5;
    const int be = blockIdx.x * 8 + g;             // b*EE + e
    const int cnt = colcnt[be];
    const int iters = min(cnt, MAXDEG);
    const int* idx = csc + (size_t)be * MAXDEG;
    const float* yb = ybuf + ((size_t)(be & ~(EE - 1))) * HID;   // behavior base
    const float s = gather_sum(yb, idx, iters, h);
    zbuf[(size_t)be * HID + h] = s * (1.0f / fmaxf((float)cnt, EPSF));
}

// ---------------------------------------------------------------------------
// K5: layer core -> x_new; then y_out[b,n,:] = dv * (x_new@Wn1+bn1)
// ---------------------------------------------------------------------------
__global__ __launch_bounds__(256) void k_layer(
        const float* __restrict__ zbuf,
        const int* __restrict__ rowcnt, const int* __restrict__ csr,
        const float* __restrict__ Theta, const float* __restrict__ bimp,
        const float* __restrict__ Wn1, const float* __restrict__ bn1,
        float* __restrict__ ybuf_out) {
    __shared__ float sTh[BB * HID * HID];
    __shared__ float sW[HID * HID];
    __shared__ float sb[HID];
    __shared__ float su[8][HID];
    __shared__ float sw[4];
    const int tid = threadIdx.x;
    for (int i = tid; i < BB * HID * HID; i += 256) sTh[i] = Theta[i];
    for (int i = tid; i < HID * HID; i += 256) sW[i] = Wn1[i];
    if (tid < HID) sb[tid] = bn1[tid];
    if (tid == 0) softmax3(bimp, sw);
    __syncthreads();
    const int h = tid & 31, loc = tid >> 5;
    const int n = blockIdx.x * 8 + loc;
    float accx = 0.f;
#pragma unroll
    for (int b = 0; b < BB; b++) {
        const int bn = (b << 12) + n;
        const int cnt = rowcnt[bn];
        const int iters = min(cnt, MAXDEG);
        const int* idx = csr + (size_t)bn * MAXDEG;
        const float* zb = zbuf + ((size_t)(b << 12)) * HID;
        const float u = gather_sum(zb, idx, iters, h) * rsqrtf(fmaxf((float)cnt, EPSF));
        su[loc][h] = u;                             // wave-internal
        float msg = 0.f;
#pragma unroll
        for (int hh = 0; hh < HID; hh++)
            msg = fmaf(su[loc][hh], sTh[b * (HID * HID) + hh * HID + h], msg);
        accx = fmaf(sw[b], msg, accx);
    }
    su[loc][h] = fmaxf(accx, 0.f);                  // x_new
    float a = sb[h];
#pragma unroll
    for (int hh = 0; hh < HID; hh++) a = fmaf(su[loc][hh], sW[hh * HID + h], a);
#pragma unroll
    for (int b = 0; b < BB; b++) {
        const float c = (float)rowcnt[(b << 12) + n];
        ybuf_out[((size_t)(b << 12) + n) * HID + h] = a * rsqrtf(fmaxf(c, EPSF));
    }
}

// ---------------------------------------------------------------------------
// K6: final layer core -> x2; projection -> out
// ---------------------------------------------------------------------------
__global__ __launch_bounds__(256) void k_final(
        const float* __restrict__ zbuf,
        const int* __restrict__ rowcnt, const int* __restrict__ csr,
        const float* __restrict__ Theta, const float* __restrict__ bimp,
        const float* __restrict__ Wp1, const float* __restrict__ bp1,
        const float* __restrict__ Wp2, const float* __restrict__ bp2,
        float* __restrict__ out) {
    __shared__ float sTh[BB * HID * HID];
    __shared__ float sW1[HID * HID], sW2[HID * HID];
    __shared__ float sb1[HID], sb2[HID];
    __shared__ float su[8][HID];
    __shared__ float sw[4];
    const int tid = threadIdx.x;
    for (int i = tid; i < BB * HID * HID; i += 256) sTh[i] = Theta[i];
    for (int i = tid; i < HID * HID; i += 256) { sW1[i] = Wp1[i]; sW2[i] = Wp2[i]; }
    if (tid < HID) { sb1[tid] = bp1[tid]; sb2[tid] = bp2[tid]; }
    if (tid == 0) softmax3(bimp, sw);
    __syncthreads();
    const int h = tid & 31, loc = tid >> 5;
    const int n = blockIdx.x * 8 + loc;
    float accx = 0.f;
#pragma unroll
    for (int b = 0; b < BB; b++) {
        const int bn = (b << 12) + n;
        const int cnt = rowcnt[bn];
        const int iters = min(cnt, MAXDEG);
        const int* idx = csr + (size_t)bn * MAXDEG;
        const float* zb = zbuf + ((size_t)(b << 12)) * HID;
        const float u = gather_sum(zb, idx, iters, h) * rsqrtf(fmaxf((float)cnt, EPSF));
        su[loc][h] = u;
        float msg = 0.f;
#pragma unroll
        for (int hh = 0; hh < HID; hh++)
            msg = fmaf(su[loc][hh], sTh[b * (HID * HID) + hh * HID + h], msg);
        accx = fmaf(sw[b], msg, accx);
    }
    su[loc][h] = fmaxf(accx, 0.f);                  // x2
    float p = sb1[h];
#pragma unroll
    for (int hh = 0; hh < HID; hh++) p = fmaf(su[loc][hh], sW1[hh * HID + h], p);
    su[loc][h] = fmaxf(p, 0.f);                     // program-order within wave
    float o = sb2[h];
#pragma unroll
    for (int hh = 0; hh < HID; hh++) o = fmaf(su[loc][hh], sW2[hh * HID + h], o);
    out[(size_t)n * HID + h] = o;
}

// ---------------------------------------------------------------------------
extern "C" void kernel_launch(void* const* d_in, const int* in_sizes, int n_in,
                              void* d_out, int out_size, void* d_ws, size_t ws_size,
                              hipStream_t stream) {
    const float* X      = (const float*)d_in[0];
    const float* H      = (const float*)d_in[1];
    const float* W_init = (const float*)d_in[2];
    const float* b_init = (const float*)d_in[3];
    const float* W_node = (const float*)d_in[4];   // [2, HID, HID]
    const float* b_node = (const float*)d_in[5];   // [2, HID]
    const float* Theta  = (const float*)d_in[6];   // [BB, HID, HID]
    const float* bimp   = (const float*)d_in[7];   // [BB]
    const float* Wp1    = (const float*)d_in[8];
    const float* bp1    = (const float*)d_in[9];
    const float* Wp2    = (const float*)d_in[10];
    const float* bp2    = (const float*)d_in[11];
    float* out = (float*)d_out;
    (void)in_sizes; (void)n_in; (void)out_size; (void)ws_size;

    char* ws = (char*)d_ws;
    size_t off = 0;
    auto alloc = [&](size_t bytes) { void* p = ws + off; off += (bytes + 255) & ~(size_t)255; return p; };
    int*   rowcnt = (int*)alloc((size_t)BB * NN * 4);
    int*   colcnt = (int*)alloc((size_t)BB * EE * 4);
    int*   csr    = (int*)alloc((size_t)BB * NN * MAXDEG * 4);
    int*   csc    = (int*)alloc((size_t)BB * EE * MAXDEG * 4);
    float* ybuf   = (float*)alloc((size_t)BB * NN * HID * 4);
    float* zbuf   = (float*)alloc((size_t)BB * EE * HID * 4);

    // 1. pure HBM stream: CSR + rowcnt (+ colcnt := 0)
    build_sparse<<<BB * NN, 256, 0, stream>>>(H, rowcnt, colcnt, csr);
    // 2. CSC from CSR (L2-resident atomics, off the HBM path)
    k_csc<<<(BB * NN) / 8, 256, 0, stream>>>(rowcnt, csr, colcnt, csc);
    // 3. y0 = dv * (relu(X@Wi+bi)@Wn0+bn0)
    k_xw0<<<NN / 8, 256, 0, stream>>>(X, W_init, b_init, W_node, b_node, rowcnt, ybuf);
    // 4. layer 0: z0 = de*H^T y0 ; u/Theta/combine ; y1 = dv*(x1@Wn1+bn1)
    k_z<<<(BB * EE) / 8, 256, 0, stream>>>(colcnt, csc, ybuf, zbuf);
    k_layer<<<NN / 8, 256, 0, stream>>>(zbuf, rowcnt, csr, Theta, bimp,
                                        W_node + HID * HID, b_node + HID, ybuf);
    // 5. layer 1: z1 = de*H^T y1 ; u/Theta/combine ; projection -> out
    k_z<<<(BB * EE) / 8, 256, 0, stream>>>(colcnt, csc, ybuf, zbuf);
    k_final<<<NN / 8, 256, 0, stream>>>(zbuf, rowcnt, csr, Theta, bimp,
                                        Wp1, bp1, Wp2, bp2, out);
}

// Round 5
// 388.679 us; speedup vs baseline: 2.0449x; 1.0069x over previous
//
#include <hip/hip_runtime.h>

// Problem constants (fixed by reference)
#define NN 4096
#define EE 4096
#define BB 3
#define DIN 64
#define HID 32
#define MAXDEG 128          // binomial(4096,0.008): mean 32.8, sd 5.7; max ~59
#define EPSF 1e-6f
#define CCPAD 32            // colcnt padded: 1 counter per 128-B line (kills
                            // line-level atomic contention: 1050 -> 33 RMW/line)

// ---------------------------------------------------------------------------
// K1: ONE pure streaming pass over H (201 MB) -> CSR + rowcnt. NO global
// atomics (R2 measured this structure at ~30 us = ~6.7 TB/s; R1/R3/R4 show
// any contended-atomic path costs ~300 us). Also zeroes this block's padded
// colcnt line for the later CSC build.
// ---------------------------------------------------------------------------
__global__ void build_sparse(const float* __restrict__ H,
                             int* __restrict__ rowcnt,
                             int* __restrict__ colcnt_pad,
                             int* __restrict__ csr) {
    __shared__ int scnt;
    const int bn = blockIdx.x;                    // b*NN + n
    if (threadIdx.x == 0) scnt = 0;
    if (threadIdx.x < CCPAD) colcnt_pad[(size_t)bn * CCPAD + threadIdx.x] = 0;
    __syncthreads();
    const float4* row = (const float4*)(H + (size_t)bn * EE);
    int* crow = csr + (size_t)bn * MAXDEG;
    for (int k = threadIdx.x; k < EE / 4; k += 256) {
        float4 v = row[k];
        int m = (v.x != 0.f) + (v.y != 0.f) + (v.z != 0.f) + (v.w != 0.f);
        if (m) {                                   // ~3% of threads per iter
            int base = atomicAdd(&scnt, m);        // LDS atomic only
            const int e0 = k * 4;
            if (v.x != 0.f) { if (base < MAXDEG) crow[base] = e0;     base++; }
            if (v.y != 0.f) { if (base < MAXDEG) crow[base] = e0 + 1; base++; }
            if (v.z != 0.f) { if (base < MAXDEG) crow[base] = e0 + 2; base++; }
            if (v.w != 0.f) { if (base < MAXDEG) crow[base] = e0 + 3; base++; }
        }
    }
    __syncthreads();
    if (threadIdx.x == 0) rowcnt[bn] = scnt;       // exact count (dv exactness)
}

// ---------------------------------------------------------------------------
// K2: CSC from CSR. Padded counters -> address-level contention only
// (~33 RMWs per line, 12288 independent chains).
// ---------------------------------------------------------------------------
__global__ __launch_bounds__(256) void k_csc(
        const int* __restrict__ rowcnt, const int* __restrict__ csr,
        int* __restrict__ colcnt_pad, int* __restrict__ csc) {
    const int tid = threadIdx.x, lane = tid & 31, g = tid >> 5;
    const int r = blockIdx.x * 8 + g;              // row index bn
    const int b = r >> 12, n = r & (NN - 1);
    const int cnt = min(rowcnt[r], MAXDEG);
    const int* row = csr + (size_t)r * MAXDEG;
    int* cc = colcnt_pad + (size_t)(b << 12) * CCPAD;
    for (int j = lane; j < cnt; j += 32) {
        const int e = row[j];
        const int slot = atomicAdd(&cc[(size_t)e * CCPAD], 1);
        if (slot < MAXDEG) csc[((size_t)(b << 12) + e) * MAXDEG + slot] = n;
    }
}

// ---------------------------------------------------------------------------
// K3: y[b,n,:] = dv[b,n] * (relu(X@Wi+bi) @ Wn0 + bn0)
// ---------------------------------------------------------------------------
__global__ __launch_bounds__(256) void k_xw0(
        const float* __restrict__ X,
        const float* __restrict__ Wi, const float* __restrict__ bi,
        const float* __restrict__ Wn0, const float* __restrict__ bn0,
        const int* __restrict__ rowcnt, float* __restrict__ ybuf) {
    __shared__ float sWi[DIN * HID];
    __shared__ float sWn[HID * HID];
    __shared__ float sb0[HID], sb1[HID];
    __shared__ float su[8][HID];
    const int tid = threadIdx.x;
    for (int i = tid; i < DIN * HID; i += 256) sWi[i] = Wi[i];
    for (int i = tid; i < HID * HID; i += 256) sWn[i] = Wn0[i];
    if (tid < HID) { sb0[tid] = bi[tid]; sb1[tid] = bn0[tid]; }
    __syncthreads();
    const int h = tid & 31, loc = tid >> 5;
    const int n = blockIdx.x * 8 + loc;
    const float* xr = X + (size_t)n * DIN;
    float acc = sb0[h];
#pragma unroll 8
    for (int d = 0; d < DIN; d++) acc = fmaf(xr[d], sWi[d * HID + h], acc);
    su[loc][h] = fmaxf(acc, 0.f);                  // wave-internal, no barrier
    float a = sb1[h];
#pragma unroll
    for (int hh = 0; hh < HID; hh++) a = fmaf(su[loc][hh], sWn[hh * HID + h], a);
#pragma unroll
    for (int b = 0; b < BB; b++) {
        const float c = (float)rowcnt[(b << 12) + n];
        ybuf[((size_t)(b << 12) + n) * HID + h] = a * rsqrtf(fmaxf(c, EPSF));
    }
}

// ---------------------------------------------------------------------------
// Pure gather: sum rows[idx[j]][h], 4 independent chains in flight
// ---------------------------------------------------------------------------
__device__ __forceinline__ float gather_sum(const float* __restrict__ base,
                                            const int* __restrict__ idx,
                                            int iters, int h) {
    float a0 = 0.f, a1 = 0.f, a2 = 0.f, a3 = 0.f;
    int j = 0;
    for (; j + 4 <= iters; j += 4) {
        int n0 = idx[j], n1 = idx[j + 1], n2 = idx[j + 2], n3 = idx[j + 3];
        a0 += base[n0 * HID + h];
        a1 += base[n1 * HID + h];
        a2 += base[n2 * HID + h];
        a3 += base[n3 * HID + h];
    }
    for (; j < iters; j++) a0 += base[idx[j] * HID + h];
    return (a0 + a1) + (a2 + a3);
}

__device__ __forceinline__ void softmax3(const float* __restrict__ bimp, float* sw) {
    float b0 = bimp[0], b1 = bimp[1], b2 = bimp[2];
    float m = fmaxf(b0, fmaxf(b1, b2));
    float e0 = expf(b0 - m), e1 = expf(b1 - m), e2 = expf(b2 - m);
    float s = e0 + e1 + e2;
    sw[0] = e0 / s; sw[1] = e1 / s; sw[2] = e2 / s;
}

// ---------------------------------------------------------------------------
// K4 (x2): z[b,e,:] = de[b,e] * sum_{n in csc(b,e)} y[b,n,:]  (pure gather)
// ---------------------------------------------------------------------------
__global__ __launch_bounds__(256) void k_z(
        const int* __restrict__ colcnt_pad, const int* __restrict__ csc,
        const float* __restrict__ ybuf, float* __restrict__ zbuf) {
    const int tid = threadIdx.x, h = tid & 31, g = tid >> 5;
    const int be = blockIdx.x * 8 + g;             // b*EE + e
    const int cnt = colcnt_pad[(size_t)be * CCPAD];
    const int iters = min(cnt, MAXDEG);
    const int* idx = csc + (size_t)be * MAXDEG;
    const float* yb = ybuf + ((size_t)(be & ~(EE - 1))) * HID;   // behavior base
    const float s = gather_sum(yb, idx, iters, h);
    zbuf[(size_t)be * HID + h] = s * (1.0f / fmaxf((float)cnt, EPSF));
}

// ---------------------------------------------------------------------------
// K5: layer core -> x_new; then y_out[b,n,:] = dv * (x_new@Wn1+bn1)
// ---------------------------------------------------------------------------
__global__ __launch_bounds__(256) void k_layer(
        const float* __restrict__ zbuf,
        const int* __restrict__ rowcnt, const int* __restrict__ csr,
        const float* __restrict__ Theta, const float* __restrict__ bimp,
        const float* __restrict__ Wn1, const float* __restrict__ bn1,
        float* __restrict__ ybuf_out) {
    __shared__ float sTh[BB * HID * HID];
    __shared__ float sW[HID * HID];
    __shared__ float sb[HID];
    __shared__ float su[8][HID];
    __shared__ float sw[4];
    const int tid = threadIdx.x;
    for (int i = tid; i < BB * HID * HID; i += 256) sTh[i] = Theta[i];
    for (int i = tid; i < HID * HID; i += 256) sW[i] = Wn1[i];
    if (tid < HID) sb[tid] = bn1[tid];
    if (tid == 0) softmax3(bimp, sw);
    __syncthreads();
    const int h = tid & 31, loc = tid >> 5;
    const int n = blockIdx.x * 8 + loc;
    float accx = 0.f;
#pragma unroll
    for (int b = 0; b < BB; b++) {
        const int bn = (b << 12) + n;
        const int cnt = rowcnt[bn];
        const int iters = min(cnt, MAXDEG);
        const int* idx = csr + (size_t)bn * MAXDEG;
        const float* zb = zbuf + ((size_t)(b << 12)) * HID;
        const float u = gather_sum(zb, idx, iters, h) * rsqrtf(fmaxf((float)cnt, EPSF));
        su[loc][h] = u;                             // wave-internal
        float msg = 0.f;
#pragma unroll
        for (int hh = 0; hh < HID; hh++)
            msg = fmaf(su[loc][hh], sTh[b * (HID * HID) + hh * HID + h], msg);
        accx = fmaf(sw[b], msg, accx);
    }
    su[loc][h] = fmaxf(accx, 0.f);                  // x_new
    float a = sb[h];
#pragma unroll
    for (int hh = 0; hh < HID; hh++) a = fmaf(su[loc][hh], sW[hh * HID + h], a);
#pragma unroll
    for (int b = 0; b < BB; b++) {
        const float c = (float)rowcnt[(b << 12) + n];
        ybuf_out[((size_t)(b << 12) + n) * HID + h] = a * rsqrtf(fmaxf(c, EPSF));
    }
}

// ---------------------------------------------------------------------------
// K6: final layer core -> x2; projection -> out
// ---------------------------------------------------------------------------
__global__ __launch_bounds__(256) void k_final(
        const float* __restrict__ zbuf,
        const int* __restrict__ rowcnt, const int* __restrict__ csr,
        const float* __restrict__ Theta, const float* __restrict__ bimp,
        const float* __restrict__ Wp1, const float* __restrict__ bp1,
        const float* __restrict__ Wp2, const float* __restrict__ bp2,
        float* __restrict__ out) {
    __shared__ float sTh[BB * HID * HID];
    __shared__ float sW1[HID * HID], sW2[HID * HID];
    __shared__ float sb1[HID], sb2[HID];
    __shared__ float su[8][HID];
    __shared__ float sw[4];
    const int tid = threadIdx.x;
    for (int i = tid; i < BB * HID * HID; i += 256) sTh[i] = Theta[i];
    for (int i = tid; i < HID * HID; i += 256) { sW1[i] = Wp1[i]; sW2[i] = Wp2[i]; }
    if (tid < HID) { sb1[tid] = bp1[tid]; sb2[tid] = bp2[tid]; }
    if (tid == 0) softmax3(bimp, sw);
    __syncthreads();
    const int h = tid & 31, loc = tid >> 5;
    const int n = blockIdx.x * 8 + loc;
    float accx = 0.f;
#pragma unroll
    for (int b = 0; b < BB; b++) {
        const int bn = (b << 12) + n;
        const int cnt = rowcnt[bn];
        const int iters = min(cnt, MAXDEG);
        const int* idx = csr + (size_t)bn * MAXDEG;
        const float* zb = zbuf + ((size_t)(b << 12)) * HID;
        const float u = gather_sum(zb, idx, iters, h) * rsqrtf(fmaxf((float)cnt, EPSF));
        su[loc][h] = u;
        float msg = 0.f;
#pragma unroll
        for (int hh = 0; hh < HID; hh++)
            msg = fmaf(su[loc][hh], sTh[b * (HID * HID) + hh * HID + h], msg);
        accx = fmaf(sw[b], msg, accx);
    }
    su[loc][h] = fmaxf(accx, 0.f);                  // x2
    float p = sb1[h];
#pragma unroll
    for (int hh = 0; hh < HID; hh++) p = fmaf(su[loc][hh], sW1[hh * HID + h], p);
    su[loc][h] = fmaxf(p, 0.f);                     // program-order within wave
    float o = sb2[h];
#pragma unroll
    for (int hh = 0; hh < HID; hh++) o = fmaf(su[loc][hh], sW2[hh * HID + h], o);
    out[(size_t)n * HID + h] = o;
}

// ---------------------------------------------------------------------------
extern "C" void kernel_launch(void* const* d_in, const int* in_sizes, int n_in,
                              void* d_out, int out_size, void* d_ws, size_t ws_size,
                              hipStream_t stream) {
    const float* X      = (const float*)d_in[0];
    const float* H      = (const float*)d_in[1];
    const float* W_init = (const float*)d_in[2];
    const float* b_init = (const float*)d_in[3];
    const float* W_node = (const float*)d_in[4];   // [2, HID, HID]
    const float* b_node = (const float*)d_in[5];   // [2, HID]
    const float* Theta  = (const float*)d_in[6];   // [BB, HID, HID]
    const float* bimp   = (const float*)d_in[7];   // [BB]
    const float* Wp1    = (const float*)d_in[8];
    const float* bp1    = (const float*)d_in[9];
    const float* Wp2    = (const float*)d_in[10];
    const float* bp2    = (const float*)d_in[11];
    float* out = (float*)d_out;
    (void)in_sizes; (void)n_in; (void)out_size; (void)ws_size;

    char* ws = (char*)d_ws;
    size_t off = 0;
    auto alloc = [&](size_t bytes) { void* p = ws + off; off += (bytes + 255) & ~(size_t)255; return p; };
    int*   rowcnt     = (int*)alloc((size_t)BB * NN * 4);
    int*   colcnt_pad = (int*)alloc((size_t)BB * EE * CCPAD * 4);   // 1.5 MB
    int*   csr        = (int*)alloc((size_t)BB * NN * MAXDEG * 4);
    int*   csc        = (int*)alloc((size_t)BB * EE * MAXDEG * 4);
    float* ybuf       = (float*)alloc((size_t)BB * NN * HID * 4);
    float* zbuf       = (float*)alloc((size_t)BB * EE * HID * 4);

    // 1. pure HBM stream: CSR + rowcnt (+ padded colcnt := 0)
    build_sparse<<<BB * NN, 256, 0, stream>>>(H, rowcnt, colcnt_pad, csr);
    // 2. CSC from CSR (padded counters -> no line-level atomic contention)
    k_csc<<<(BB * NN) / 8, 256, 0, stream>>>(rowcnt, csr, colcnt_pad, csc);
    // 3. y0 = dv * (relu(X@Wi+bi)@Wn0+bn0)
    k_xw0<<<NN / 8, 256, 0, stream>>>(X, W_init, b_init, W_node, b_node, rowcnt, ybuf);
    // 4. layer 0: z0 = de*H^T y0 ; u/Theta/combine ; y1 = dv*(x1@Wn1+bn1)
    k_z<<<(BB * EE) / 8, 256, 0, stream>>>(colcnt_pad, csc, ybuf, zbuf);
    k_layer<<<NN / 8, 256, 0, stream>>>(zbuf, rowcnt, csr, Theta, bimp,
                                        W_node + HID * HID, b_node + HID, ybuf);
    // 5. layer 1: z1 = de*H^T y1 ; u/Theta/combine ; projection -> out
    k_z<<<(BB * EE) / 8, 256, 0, stream>>>(colcnt_pad, csc, ybuf, zbuf);
    k_final<<<NN / 8, 256, 0, stream>>>(zbuf, rowcnt, csr, Theta, bimp,
                                        Wp1, bp1, Wp2, bp2, out);
}

// Round 6
// 377.663 us; speedup vs baseline: 2.1045x; 1.0292x over previous
//
#include <hip/hip_runtime.h>

// Problem constants (fixed by reference)
#define NN 4096
#define EE 4096
#define BB 3
#define DIN 64
#define HID 32
#define MAXDEG 80           // binomial(4096,0.008): mean 32.8, sd 5.7, max~59.
                            // 80 = 8.3 sigma; R1-R5 passed with exact counts.
#define EPSF 1e-6f
#define CCPAD 32            // colcnt: 1 counter per 128-B line

// ---------------------------------------------------------------------------
// K1: ONE pure streaming pass over H (201 MB) -> CSR (ABSOLUTE edge ids
// b*EE+e) + rowcnt. NO global atomics (R2 measured ~30 us; any contended
// atomic path in-stream costs ~10x). Zeroes this row's padded colcnt line.
// ---------------------------------------------------------------------------
__global__ void build_sparse(const float* __restrict__ H,
                             int* __restrict__ rowcnt,
                             int* __restrict__ colcnt_pad,
                             int* __restrict__ csr) {
    __shared__ int scnt;
    const int bn = blockIdx.x;                    // absolute node row r = b*NN+n
    if (threadIdx.x == 0) scnt = 0;
    if (threadIdx.x < CCPAD) colcnt_pad[(size_t)bn * CCPAD + threadIdx.x] = 0;
    __syncthreads();
    const float4* row = (const float4*)(H + (size_t)bn * EE);
    int* crow = csr + (size_t)bn * MAXDEG;
    const int ebase = bn & ~(NN - 1);             // b*EE (EE==NN)
    for (int k = threadIdx.x; k < EE / 4; k += 256) {
        float4 v = row[k];
        int m = (v.x != 0.f) + (v.y != 0.f) + (v.z != 0.f) + (v.w != 0.f);
        if (m) {                                   // ~3% of threads per iter
            int base = atomicAdd(&scnt, m);        // LDS atomic only
            const int e0 = ebase + k * 4;          // absolute edge id
            if (v.x != 0.f) { if (base < MAXDEG) crow[base] = e0;     base++; }
            if (v.y != 0.f) { if (base < MAXDEG) crow[base] = e0 + 1; base++; }
            if (v.z != 0.f) { if (base < MAXDEG) crow[base] = e0 + 2; base++; }
            if (v.w != 0.f) { if (base < MAXDEG) crow[base] = e0 + 3; base++; }
        }
    }
    __syncthreads();
    if (threadIdx.x == 0) rowcnt[bn] = scnt;       // exact count (dv exactness)
}

// ---------------------------------------------------------------------------
// K2: CSC from CSR (absolute ids both ways). Lane-parallel, <=2 atomics/lane.
// ---------------------------------------------------------------------------
__global__ __launch_bounds__(256) void k_csc(
        const int* __restrict__ rowcnt, const int* __restrict__ csr,
        int* __restrict__ colcnt_pad, int* __restrict__ csc) {
    const int tid = threadIdx.x, lane = tid & 31, g = tid >> 5;
    const int r = blockIdx.x * 8 + g;              // absolute node row
    const int cnt = min(rowcnt[r], MAXDEG);
    const int* row = csr + (size_t)r * MAXDEG;
    for (int j = lane; j < cnt; j += 32) {
        const int E = row[j];                      // absolute edge id
        const int slot = atomicAdd(&colcnt_pad[(size_t)E * CCPAD], 1);
        if (slot < MAXDEG) csc[(size_t)E * MAXDEG + slot] = r;
    }
}

// ---------------------------------------------------------------------------
// Shallow-chain gather: 2 coalesced index loads + shfl broadcast; all data
// gathers independent (8 accumulator chains). Address-chain depth = 2 memory
// rounds instead of ~8 (the R5 sink: HBM/cross-XCD latency chains).
// Loads are always in-bounds: indices sanitized to 0 for j>=m; adds masked.
// ---------------------------------------------------------------------------
__device__ __forceinline__ float gather32(const float* __restrict__ base,
                                          const int* __restrict__ row,
                                          int m, int lane, int h) {
    int i0 = row[lane];        // stride MAXDEG=80 >= 64: always in-bounds
    int i1 = row[lane + 32];
    if (lane >= m) i0 = 0;     // sanitize (poisoned tail) -> row 0, add masked
    if (lane + 32 >= m) i1 = 0;
    float a0 = 0.f, a1 = 0.f, a2 = 0.f, a3 = 0.f;
    float a4 = 0.f, a5 = 0.f, a6 = 0.f, a7 = 0.f;
    for (int j0 = 0; j0 < m; j0 += 8) {
#pragma unroll
        for (int k = 0; k < 8; k++) {
            const int j = j0 + k;
            const int e = __shfl((j & 32) ? i1 : i0, j & 31, 32);
            const float v = base[(size_t)e * HID + h];   // always safe
            float* acc = (k == 0) ? &a0 : (k == 1) ? &a1 : (k == 2) ? &a2 :
                         (k == 3) ? &a3 : (k == 4) ? &a4 : (k == 5) ? &a5 :
                         (k == 6) ? &a6 : &a7;
            if (j < m) *acc += v;
        }
    }
    return ((a0 + a1) + (a2 + a3)) + ((a4 + a5) + (a6 + a7));
}

__device__ __forceinline__ void softmax3(const float* __restrict__ bimp, float* sw) {
    float b0 = bimp[0], b1 = bimp[1], b2 = bimp[2];
    float m = fmaxf(b0, fmaxf(b1, b2));
    float e0 = expf(b0 - m), e1 = expf(b1 - m), e2 = expf(b2 - m);
    float s = e0 + e1 + e2;
    sw[0] = e0 / s; sw[1] = e1 / s; sw[2] = e2 / s;
}

// ---------------------------------------------------------------------------
// K3: y[r,:] = dv[r] * (relu(X@Wi+bi) @ Wn0 + bn0),  r = b*NN+n
// ---------------------------------------------------------------------------
__global__ __launch_bounds__(256) void k_xw0(
        const float* __restrict__ X,
        const float* __restrict__ Wi, const float* __restrict__ bi,
        const float* __restrict__ Wn0, const float* __restrict__ bn0,
        const int* __restrict__ rowcnt, float* __restrict__ ybuf) {
    __shared__ float sWi[DIN * HID];
    __shared__ float sWn[HID * HID];
    __shared__ float sb0[HID], sb1[HID];
    __shared__ float su[8][HID];
    const int tid = threadIdx.x;
    for (int i = tid; i < DIN * HID; i += 256) sWi[i] = Wi[i];
    for (int i = tid; i < HID * HID; i += 256) sWn[i] = Wn0[i];
    if (tid < HID) { sb0[tid] = bi[tid]; sb1[tid] = bn0[tid]; }
    __syncthreads();
    const int h = tid & 31, loc = tid >> 5;
    const int n = blockIdx.x * 8 + loc;
    const float* xr = X + (size_t)n * DIN;
    float acc = sb0[h];
#pragma unroll 8
    for (int d = 0; d < DIN; d++) acc = fmaf(xr[d], sWi[d * HID + h], acc);
    su[loc][h] = fmaxf(acc, 0.f);                  // wave-internal, no barrier
    float a = sb1[h];
#pragma unroll
    for (int hh = 0; hh < HID; hh++) a = fmaf(su[loc][hh], sWn[hh * HID + h], a);
#pragma unroll
    for (int b = 0; b < BB; b++) {
        const float c = (float)rowcnt[(b << 12) + n];
        ybuf[((size_t)(b << 12) + n) * HID + h] = a * rsqrtf(fmaxf(c, EPSF));
    }
}

// ---------------------------------------------------------------------------
// K4 (x2): z[q,:] = de[q] * sum_{r in csc(q)} y[r,:]   (shallow-chain gather)
// ---------------------------------------------------------------------------
__global__ __launch_bounds__(256) void k_z(
        const int* __restrict__ colcnt_pad, const int* __restrict__ csc,
        const float* __restrict__ ybuf, float* __restrict__ zbuf) {
    const int tid = threadIdx.x, h = tid & 31, g = tid >> 5;
    const int q = blockIdx.x * 8 + g;              // absolute edge id
    const int cnt = colcnt_pad[(size_t)q * CCPAD];
    const int m = min(cnt, MAXDEG);
    const float s = gather32(ybuf, csc + (size_t)q * MAXDEG, m, h, h);
    zbuf[(size_t)q * HID + h] = s * (1.0f / fmaxf((float)cnt, EPSF));
}

// ---------------------------------------------------------------------------
// K5: layer core -> x_new; then y_out[r,:] = dv * (x_new@Wn1+bn1)
// ---------------------------------------------------------------------------
__global__ __launch_bounds__(256) void k_layer(
        const float* __restrict__ zbuf,
        const int* __restrict__ rowcnt, const int* __restrict__ csr,
        const float* __restrict__ Theta, const float* __restrict__ bimp,
        const float* __restrict__ Wn1, const float* __restrict__ bn1,
        float* __restrict__ ybuf_out) {
    __shared__ float sTh[BB * HID * HID];
    __shared__ float sW[HID * HID];
    __shared__ float sb[HID];
    __shared__ float su[8][HID];
    __shared__ float sw[4];
    const int tid = threadIdx.x;
    for (int i = tid; i < BB * HID * HID; i += 256) sTh[i] = Theta[i];
    for (int i = tid; i < HID * HID; i += 256) sW[i] = Wn1[i];
    if (tid < HID) sb[tid] = bn1[tid];
    if (tid == 0) softmax3(bimp, sw);
    __syncthreads();
    const int h = tid & 31, loc = tid >> 5;
    const int n = blockIdx.x * 8 + loc;
    float accx = 0.f;
#pragma unroll
    for (int b = 0; b < BB; b++) {
        const int r = (b << 12) + n;
        const int cnt = rowcnt[r];
        const int m = min(cnt, MAXDEG);
        const float u = gather32(zbuf, csr + (size_t)r * MAXDEG, m, h, h)
                        * rsqrtf(fmaxf((float)cnt, EPSF));
        su[loc][h] = u;                             // wave-internal
        float msg = 0.f;
#pragma unroll
        for (int hh = 0; hh < HID; hh++)
            msg = fmaf(su[loc][hh], sTh[b * (HID * HID) + hh * HID + h], msg);
        accx = fmaf(sw[b], msg, accx);
    }
    su[loc][h] = fmaxf(accx, 0.f);                  // x_new
    float a = sb[h];
#pragma unroll
    for (int hh = 0; hh < HID; hh++) a = fmaf(su[loc][hh], sW[hh * HID + h], a);
#pragma unroll
    for (int b = 0; b < BB; b++) {
        const float c = (float)rowcnt[(b << 12) + n];
        ybuf_out[((size_t)(b << 12) + n) * HID + h] = a * rsqrtf(fmaxf(c, EPSF));
    }
}

// ---------------------------------------------------------------------------
// K6: final layer core -> x2; projection -> out
// ---------------------------------------------------------------------------
__global__ __launch_bounds__(256) void k_final(
        const float* __restrict__ zbuf,
        const int* __restrict__ rowcnt, const int* __restrict__ csr,
        const float* __restrict__ Theta, const float* __restrict__ bimp,
        const float* __restrict__ Wp1, const float* __restrict__ bp1,
        const float* __restrict__ Wp2, const float* __restrict__ bp2,
        float* __restrict__ out) {
    __shared__ float sTh[BB * HID * HID];
    __shared__ float sW1[HID * HID], sW2[HID * HID];
    __shared__ float sb1[HID], sb2[HID];
    __shared__ float su[8][HID];
    __shared__ float sw[4];
    const int tid = threadIdx.x;
    for (int i = tid; i < BB * HID * HID; i += 256) sTh[i] = Theta[i];
    for (int i = tid; i < HID * HID; i += 256) { sW1[i] = Wp1[i]; sW2[i] = Wp2[i]; }
    if (tid < HID) { sb1[tid] = bp1[tid]; sb2[tid] = bp2[tid]; }
    if (tid == 0) softmax3(bimp, sw);
    __syncthreads();
    const int h = tid & 31, loc = tid >> 5;
    const int n = blockIdx.x * 8 + loc;
    float accx = 0.f;
#pragma unroll
    for (int b = 0; b < BB; b++) {
        const int r = (b << 12) + n;
        const int cnt = rowcnt[r];
        const int m = min(cnt, MAXDEG);
        const float u = gather32(zbuf, csr + (size_t)r * MAXDEG, m, h, h)
                        * rsqrtf(fmaxf((float)cnt, EPSF));
        su[loc][h] = u;
        float msg = 0.f;
#pragma unroll
        for (int hh = 0; hh < HID; hh++)
            msg = fmaf(su[loc][hh], sTh[b * (HID * HID) + hh * HID + h], msg);
        accx = fmaf(sw[b], msg, accx);
    }
    su[loc][h] = fmaxf(accx, 0.f);                  // x2
    float p = sb1[h];
#pragma unroll
    for (int hh = 0; hh < HID; hh++) p = fmaf(su[loc][hh], sW1[hh * HID + h], p);
    su[loc][h] = fmaxf(p, 0.f);                     // program-order within wave
    float o = sb2[h];
#pragma unroll
    for (int hh = 0; hh < HID; hh++) o = fmaf(su[loc][hh], sW2[hh * HID + h], o);
    out[(size_t)n * HID + h] = o;
}

// ---------------------------------------------------------------------------
extern "C" void kernel_launch(void* const* d_in, const int* in_sizes, int n_in,
                              void* d_out, int out_size, void* d_ws, size_t ws_size,
                              hipStream_t stream) {
    const float* X      = (const float*)d_in[0];
    const float* H      = (const float*)d_in[1];
    const float* W_init = (const float*)d_in[2];
    const float* b_init = (const float*)d_in[3];
    const float* W_node = (const float*)d_in[4];   // [2, HID, HID]
    const float* b_node = (const float*)d_in[5];   // [2, HID]
    const float* Theta  = (const float*)d_in[6];   // [BB, HID, HID]
    const float* bimp   = (const float*)d_in[7];   // [BB]
    const float* Wp1    = (const float*)d_in[8];
    const float* bp1    = (const float*)d_in[9];
    const float* Wp2    = (const float*)d_in[10];
    const float* bp2    = (const float*)d_in[11];
    float* out = (float*)d_out;
    (void)in_sizes; (void)n_in; (void)out_size; (void)ws_size;

    char* ws = (char*)d_ws;
    size_t off = 0;
    auto alloc = [&](size_t bytes) { void* p = ws + off; off += (bytes + 255) & ~(size_t)255; return p; };
    int*   rowcnt     = (int*)alloc((size_t)BB * NN * 4);
    int*   colcnt_pad = (int*)alloc((size_t)BB * EE * CCPAD * 4);   // 1.5 MB
    int*   csr        = (int*)alloc((size_t)BB * NN * MAXDEG * 4);  // 3.9 MB
    int*   csc        = (int*)alloc((size_t)BB * EE * MAXDEG * 4);  // 3.9 MB
    float* ybuf       = (float*)alloc((size_t)BB * NN * HID * 4);   // 1.5 MB
    float* zbuf       = (float*)alloc((size_t)BB * EE * HID * 4);   // 1.5 MB

    // 1. pure HBM stream: CSR + rowcnt (+ padded colcnt := 0)
    build_sparse<<<BB * NN, 256, 0, stream>>>(H, rowcnt, colcnt_pad, csr);
    // 2. CSC from CSR
    k_csc<<<(BB * NN) / 8, 256, 0, stream>>>(rowcnt, csr, colcnt_pad, csc);
    // 3. y0 = dv * (relu(X@Wi+bi)@Wn0+bn0)
    k_xw0<<<NN / 8, 256, 0, stream>>>(X, W_init, b_init, W_node, b_node, rowcnt, ybuf);
    // 4. layer 0
    k_z<<<(BB * EE) / 8, 256, 0, stream>>>(colcnt_pad, csc, ybuf, zbuf);
    k_layer<<<NN / 8, 256, 0, stream>>>(zbuf, rowcnt, csr, Theta, bimp,
                                        W_node + HID * HID, b_node + HID, ybuf);
    // 5. layer 1 + projection
    k_z<<<(BB * EE) / 8, 256, 0, stream>>>(colcnt_pad, csc, ybuf, zbuf);
    k_final<<<NN / 8, 256, 0, stream>>>(zbuf, rowcnt, csr, Theta, bimp,
                                        Wp1, bp1, Wp2, bp2, out);
}

// Round 7
// 362.711 us; speedup vs baseline: 2.1913x; 1.0412x over previous
//
#include <hip/hip_runtime.h>

// Problem constants (fixed by reference)
#define NN 4096
#define EE 4096
#define BB 3
#define DIN 64
#define HID 32
#define MAXDEG 64           // binomial(4096,0.008): mean 32.8, sd 5.66;
                            // expected max over 24576 rows ~58. 64 ids x
                            // ushort = 128 B = ONE cache line per row.
#define EPSF 1e-6f
#define CCPAD 8             // colcnt stride (ints); only [0] is the counter

// ---------------------------------------------------------------------------
// K1: ONE pure streaming pass over H (201 MB) -> csr16 (ushort relative ids,
// zero-filled tail) + exact rowcnt. NO global atomics in the stream (R2
// measured ~30 us; atomic-polluted variants cost ~10x). Also pre-zeroes this
// row's csc16 line and colcnt_pad entry for k_prep.
// ---------------------------------------------------------------------------
__global__ void build_sparse(const float* __restrict__ H,
                             int* __restrict__ rowcnt,
                             int* __restrict__ colcnt_pad,
                             unsigned short* __restrict__ csr16,
                             unsigned short* __restrict__ csc16) {
    __shared__ int el[MAXDEG];
    __shared__ int scnt;
    const int bn = blockIdx.x;                    // absolute row r = b*NN+n
    const int tid = threadIdx.x;
    if (tid == 0) scnt = 0;
    if (tid < 32) ((unsigned int*)csc16)[bn * 32 + tid] = 0;   // zero csc row
    if (tid < CCPAD) colcnt_pad[bn * CCPAD + tid] = 0;
    __syncthreads();
    const float4* row = (const float4*)(H + (size_t)bn * EE);
    for (int k = tid; k < EE / 4; k += 256) {
        float4 v = row[k];
        int m = (v.x != 0.f) + (v.y != 0.f) + (v.z != 0.f) + (v.w != 0.f);
        if (m) {                                   // ~3% of threads per iter
            int base = atomicAdd(&scnt, m);        // LDS atomic only
            const int e0 = k * 4;                  // relative edge id 0..4095
            if (v.x != 0.f) { if (base < MAXDEG) el[base] = e0;     base++; }
            if (v.y != 0.f) { if (base < MAXDEG) el[base] = e0 + 1; base++; }
            if (v.z != 0.f) { if (base < MAXDEG) el[base] = e0 + 2; base++; }
            if (v.w != 0.f) { if (base < MAXDEG) el[base] = e0 + 3; base++; }
        }
    }
    __syncthreads();
    const int cnt = scnt;
    if (tid == 0) rowcnt[bn] = cnt;                // exact count (dv exactness)
    const int m = min(cnt, MAXDEG);
    if (tid < MAXDEG)                              // zero-filled tail
        csr16[(size_t)bn * MAXDEG + tid] = (tid < m) ? (unsigned short)el[tid] : 0;
}

// ---------------------------------------------------------------------------
// K2 (merged): A) csc16 from csr16 (atomic slot append, L2-resident);
//              B) first 512 blocks also compute
//                 y0[r,:] = dv[r] * (relu(X@Wi+bi)@Wn0+bn0)
// ---------------------------------------------------------------------------
__global__ __launch_bounds__(256) void k_prep(
        const int* __restrict__ rowcnt, const unsigned short* __restrict__ csr16,
        int* __restrict__ colcnt_pad, unsigned short* __restrict__ csc16,
        const float* __restrict__ X,
        const float* __restrict__ Wi, const float* __restrict__ bi,
        const float* __restrict__ Wn0, const float* __restrict__ bn0,
        float* __restrict__ ybuf) {
    __shared__ float sWi[DIN * HID];
    __shared__ float sWn[HID * HID];
    __shared__ float sb0[HID], sb1[HID];
    __shared__ float su[8][HID];
    const int tid = threadIdx.x, lane = tid & 31, g = tid >> 5;
    // ---- part B: xw0 for first 512 blocks (uniform per-block branch) ----
    if (blockIdx.x < NN / 8) {
        for (int i = tid; i < DIN * HID; i += 256) sWi[i] = Wi[i];
        for (int i = tid; i < HID * HID; i += 256) sWn[i] = Wn0[i];
        if (tid < HID) { sb0[tid] = bi[tid]; sb1[tid] = bn0[tid]; }
        __syncthreads();
        const int n = blockIdx.x * 8 + g;
        const float* xr = X + (size_t)n * DIN;
        float acc = sb0[lane];
#pragma unroll 8
        for (int d = 0; d < DIN; d++) acc = fmaf(xr[d], sWi[d * HID + lane], acc);
        su[g][lane] = fmaxf(acc, 0.f);             // wave-internal
        float a = sb1[lane];
#pragma unroll
        for (int hh = 0; hh < HID; hh++) a = fmaf(su[g][hh], sWn[hh * HID + lane], a);
#pragma unroll
        for (int b = 0; b < BB; b++) {
            const float c = (float)rowcnt[(b << 12) + n];
            ybuf[((size_t)(b << 12) + n) * HID + lane] = a * rsqrtf(fmaxf(c, EPSF));
        }
    }
    // ---- part A: csc append (one 32-lane group per node-row) ----
    const int r = blockIdx.x * 8 + g;              // absolute node row
    const int b = r >> 12, nrel = r & (NN - 1);
    const int m = min(rowcnt[r], MAXDEG);
    const unsigned int packed = ((const unsigned int*)csr16)[r * 32 + lane];
    const int j0 = 2 * lane, j1 = 2 * lane + 1;
    if (j0 < m) {
        const int e = (int)(packed & 0xffffu);
        const int q = (b << 12) + e;
        const int slot = atomicAdd(&colcnt_pad[q * CCPAD], 1);
        if (slot < MAXDEG) csc16[(size_t)q * MAXDEG + slot] = (unsigned short)nrel;
    }
    if (j1 < m) {
        const int e = (int)(packed >> 16);
        const int q = (b << 12) + e;
        const int slot = atomicAdd(&colcnt_pad[q * CCPAD], 1);
        if (slot < MAXDEG) csc16[(size_t)q * MAXDEG + slot] = (unsigned short)nrel;
    }
}

// ---------------------------------------------------------------------------
// Gather: ONE 128-B index-line load (uint per lane = 2 ushort ids), shfl
// broadcast, then up to 64 independent data gathers on 8 accumulator chains.
// Tail ids are 0 (zero-filled) -> loads always in-bounds; adds masked.
// ---------------------------------------------------------------------------
__device__ __forceinline__ float gather16(const float* __restrict__ base,
                                          const unsigned int* __restrict__ row32,
                                          int m, int lane, int h) {
    const unsigned int packed = row32[lane];
    float a0 = 0.f, a1 = 0.f, a2 = 0.f, a3 = 0.f;
    float a4 = 0.f, a5 = 0.f, a6 = 0.f, a7 = 0.f;
    for (int j0 = 0; j0 < m; j0 += 8) {
#pragma unroll
        for (int k = 0; k < 8; k++) {
            const int j = j0 + k;
            const unsigned int p = __shfl(packed, j >> 1, 32);
            const int e = (j & 1) ? (int)(p >> 16) : (int)(p & 0xffffu);
            const float v = base[e * HID + h];     // always in-bounds
            float* acc = (k == 0) ? &a0 : (k == 1) ? &a1 : (k == 2) ? &a2 :
                         (k == 3) ? &a3 : (k == 4) ? &a4 : (k == 5) ? &a5 :
                         (k == 6) ? &a6 : &a7;
            if (j < m) *acc += v;
        }
    }
    return ((a0 + a1) + (a2 + a3)) + ((a4 + a5) + (a6 + a7));
}

__device__ __forceinline__ void softmax3(const float* __restrict__ bimp, float* sw) {
    float b0 = bimp[0], b1 = bimp[1], b2 = bimp[2];
    float m = fmaxf(b0, fmaxf(b1, b2));
    float e0 = expf(b0 - m), e1 = expf(b1 - m), e2 = expf(b2 - m);
    float s = e0 + e1 + e2;
    sw[0] = e0 / s; sw[1] = e1 / s; sw[2] = e2 / s;
}

// ---------------------------------------------------------------------------
// K3 (x2): z[q,:] = de[q] * sum_{n in csc(q)} y[b,n,:]
// ---------------------------------------------------------------------------
__global__ __launch_bounds__(256) void k_z(
        const int* __restrict__ colcnt_pad, const unsigned short* __restrict__ csc16,
        const float* __restrict__ ybuf, float* __restrict__ zbuf) {
    const int tid = threadIdx.x, h = tid & 31, g = tid >> 5;
    const int q = blockIdx.x * 8 + g;              // absolute edge row
    const int cnt = colcnt_pad[q * CCPAD];
    const int m = min(cnt, MAXDEG);
    const float* yb = ybuf + (size_t)(q & ~(EE - 1)) * HID;   // behavior base
    const float s = gather16(yb, (const unsigned int*)csc16 + q * 32, m, h, h);
    zbuf[(size_t)q * HID + h] = s * (1.0f / fmaxf((float)cnt, EPSF));
}

// ---------------------------------------------------------------------------
// K4: layer core -> x_new; then y_out[r,:] = dv * (x_new@Wn1+bn1)
// ---------------------------------------------------------------------------
__global__ __launch_bounds__(256) void k_layer(
        const float* __restrict__ zbuf,
        const int* __restrict__ rowcnt, const unsigned short* __restrict__ csr16,
        const float* __restrict__ Theta, const float* __restrict__ bimp,
        const float* __restrict__ Wn1, const float* __restrict__ bn1,
        float* __restrict__ ybuf_out) {
    __shared__ float sTh[BB * HID * HID];
    __shared__ float sW[HID * HID];
    __shared__ float sb[HID];
    __shared__ float su[8][HID];
    __shared__ float sw[4];
    const int tid = threadIdx.x;
    for (int i = tid; i < BB * HID * HID; i += 256) sTh[i] = Theta[i];
    for (int i = tid; i < HID * HID; i += 256) sW[i] = Wn1[i];
    if (tid < HID) sb[tid] = bn1[tid];
    if (tid == 0) softmax3(bimp, sw);
    __syncthreads();
    const int h = tid & 31, loc = tid >> 5;
    const int n = blockIdx.x * 8 + loc;
    float accx = 0.f;
#pragma unroll
    for (int b = 0; b < BB; b++) {
        const int r = (b << 12) + n;
        const int cnt = rowcnt[r];
        const int m = min(cnt, MAXDEG);
        const float u = gather16(zbuf + (size_t)(b << 12) * HID,
                                 (const unsigned int*)csr16 + r * 32, m, h, h)
                        * rsqrtf(fmaxf((float)cnt, EPSF));
        su[loc][h] = u;                             // wave-internal
        float msg = 0.f;
#pragma unroll
        for (int hh = 0; hh < HID; hh++)
            msg = fmaf(su[loc][hh], sTh[b * (HID * HID) + hh * HID + h], msg);
        accx = fmaf(sw[b], msg, accx);
    }
    su[loc][h] = fmaxf(accx, 0.f);                  // x_new
    float a = sb[h];
#pragma unroll
    for (int hh = 0; hh < HID; hh++) a = fmaf(su[loc][hh], sW[hh * HID + h], a);
#pragma unroll
    for (int b = 0; b < BB; b++) {
        const float c = (float)rowcnt[(b << 12) + n];
        ybuf_out[((size_t)(b << 12) + n) * HID + h] = a * rsqrtf(fmaxf(c, EPSF));
    }
}

// ---------------------------------------------------------------------------
// K5: final layer core -> x2; projection -> out
// ---------------------------------------------------------------------------
__global__ __launch_bounds__(256) void k_final(
        const float* __restrict__ zbuf,
        const int* __restrict__ rowcnt, const unsigned short* __restrict__ csr16,
        const float* __restrict__ Theta, const float* __restrict__ bimp,
        const float* __restrict__ Wp1, const float* __restrict__ bp1,
        const float* __restrict__ Wp2, const float* __restrict__ bp2,
        float* __restrict__ out) {
    __shared__ float sTh[BB * HID * HID];
    __shared__ float sW1[HID * HID], sW2[HID * HID];
    __shared__ float sb1[HID], sb2[HID];
    __shared__ float su[8][HID];
    __shared__ float sw[4];
    const int tid = threadIdx.x;
    for (int i = tid; i < BB * HID * HID; i += 256) sTh[i] = Theta[i];
    for (int i = tid; i < HID * HID; i += 256) { sW1[i] = Wp1[i]; sW2[i] = Wp2[i]; }
    if (tid < HID) { sb1[tid] = bp1[tid]; sb2[tid] = bp2[tid]; }
    if (tid == 0) softmax3(bimp, sw);
    __syncthreads();
    const int h = tid & 31, loc = tid >> 5;
    const int n = blockIdx.x * 8 + loc;
    float accx = 0.f;
#pragma unroll
    for (int b = 0; b < BB; b++) {
        const int r = (b << 12) + n;
        const int cnt = rowcnt[r];
        const int m = min(cnt, MAXDEG);
        const float u = gather16(zbuf + (size_t)(b << 12) * HID,
                                 (const unsigned int*)csr16 + r * 32, m, h, h)
                        * rsqrtf(fmaxf((float)cnt, EPSF));
        su[loc][h] = u;
        float msg = 0.f;
#pragma unroll
        for (int hh = 0; hh < HID; hh++)
            msg = fmaf(su[loc][hh], sTh[b * (HID * HID) + hh * HID + h], msg);
        accx = fmaf(sw[b], msg, accx);
    }
    su[loc][h] = fmaxf(accx, 0.f);                  // x2
    float p = sb1[h];
#pragma unroll
    for (int hh = 0; hh < HID; hh++) p = fmaf(su[loc][hh], sW1[hh * HID + h], p);
    su[loc][h] = fmaxf(p, 0.f);                     // program-order within wave
    float o = sb2[h];
#pragma unroll
    for (int hh = 0; hh < HID; hh++) o = fmaf(su[loc][hh], sW2[hh * HID + h], o);
    out[(size_t)n * HID + h] = o;
}

// ---------------------------------------------------------------------------
extern "C" void kernel_launch(void* const* d_in, const int* in_sizes, int n_in,
                              void* d_out, int out_size, void* d_ws, size_t ws_size,
                              hipStream_t stream) {
    const float* X      = (const float*)d_in[0];
    const float* H      = (const float*)d_in[1];
    const float* W_init = (const float*)d_in[2];
    const float* b_init = (const float*)d_in[3];
    const float* W_node = (const float*)d_in[4];   // [2, HID, HID]
    const float* b_node = (const float*)d_in[5];   // [2, HID]
    const float* Theta  = (const float*)d_in[6];   // [BB, HID, HID]
    const float* bimp   = (const float*)d_in[7];   // [BB]
    const float* Wp1    = (const float*)d_in[8];
    const float* bp1    = (const float*)d_in[9];
    const float* Wp2    = (const float*)d_in[10];
    const float* bp2    = (const float*)d_in[11];
    float* out = (float*)d_out;
    (void)in_sizes; (void)n_in; (void)out_size; (void)ws_size;

    char* ws = (char*)d_ws;
    size_t off = 0;
    auto alloc = [&](size_t bytes) { void* p = ws + off; off += (bytes + 255) & ~(size_t)255; return p; };
    int*            rowcnt     = (int*)alloc((size_t)BB * NN * 4);
    int*            colcnt_pad = (int*)alloc((size_t)BB * EE * CCPAD * 4);   // 384 KB
    unsigned short* csr16      = (unsigned short*)alloc((size_t)BB * NN * MAXDEG * 2); // 1.5 MB
    unsigned short* csc16      = (unsigned short*)alloc((size_t)BB * EE * MAXDEG * 2); // 1.5 MB
    float*          ybuf       = (float*)alloc((size_t)BB * NN * HID * 4);   // 1.5 MB
    float*          zbuf       = (float*)alloc((size_t)BB * EE * HID * 4);   // 1.5 MB

    // 1. pure HBM stream: csr16 + rowcnt (+ zero csc16 rows, colcnt)
    build_sparse<<<BB * NN, 256, 0, stream>>>(H, rowcnt, colcnt_pad, csr16, csc16);
    // 2. csc16 from csr16 + y0 (merged)
    k_prep<<<(BB * NN) / 8, 256, 0, stream>>>(rowcnt, csr16, colcnt_pad, csc16,
                                              X, W_init, b_init, W_node, b_node, ybuf);
    // 3. layer 0
    k_z<<<(BB * EE) / 8, 256, 0, stream>>>(colcnt_pad, csc16, ybuf, zbuf);
    k_layer<<<NN / 8, 256, 0, stream>>>(zbuf, rowcnt, csr16, Theta, bimp,
                                        W_node + HID * HID, b_node + HID, ybuf);
    // 4. layer 1 + projection
    k_z<<<(BB * EE) / 8, 256, 0, stream>>>(colcnt_pad, csc16, ybuf, zbuf);
    k_final<<<NN / 8, 256, 0, stream>>>(zbuf, rowcnt, csr16, Theta, bimp,
                                        Wp1, bp1, Wp2, bp2, out);
}

// Round 8
// 344.315 us; speedup vs baseline: 2.3084x; 1.0534x over previous
//
#include <hip/hip_runtime.h>

// Problem constants (fixed by reference)
#define NN 4096
#define EE 4096
#define BB 3
#define DIN 64
#define HID 32
#define MAXDEG 64           // binomial(4096,0.008): mean 32.8, sd 5.66;
                            // expected max over 24576 rows ~58. 64 ushort
                            // ids = 128 B = ONE cache line per row.
#define EPSF 1e-6f

// ---------------------------------------------------------------------------
// K0: zero colcnt (the only array that must start at 0; ws is poisoned 0xAA
// before every call). 48 KB.
// ---------------------------------------------------------------------------
__global__ void k_zero(int* __restrict__ p, int n) {
    const int i = blockIdx.x * 256 + threadIdx.x;
    if (i < n) p[i] = 0;
}

// ---------------------------------------------------------------------------
// K1: ONE pass over H (201 MB) does ALL graph construction:
//   - stream row (b,n) -> LDS edge list (no global atomics in the stream
//     loop; R2 measured this at ~30 us, in-loop atomics cost ~10x)
//   - csr16 row (zero tail), exact rowcnt, dvinv = rsqrt(max(cnt,eps))
//   - csc append AFTER the stream: <=64 device atomics + ushort stores per
//     block (disjoint-byte line sharing across XCDs is merged by byte-mask
//     writeback; R7's k_prep already validated this)
//   - b==0 blocks: xw0[n,:] = relu(X@Wi+bi)@Wn0+bn0  (wave-0 only)
// ---------------------------------------------------------------------------
__global__ __launch_bounds__(256) void build_all(
        const float* __restrict__ H, const float* __restrict__ X,
        const float* __restrict__ Wi, const float* __restrict__ bi,
        const float* __restrict__ Wn0, const float* __restrict__ bn0,
        int* __restrict__ rowcnt, float* __restrict__ dvinv,
        int* __restrict__ colcnt,
        unsigned short* __restrict__ csr16, unsigned short* __restrict__ csc16,
        float* __restrict__ xw0) {
    __shared__ int el[MAXDEG];
    __shared__ int scnt;
    __shared__ float sh[HID];
    const int bn = blockIdx.x, tid = threadIdx.x;
    const int b = bn >> 12, nrel = bn & (NN - 1);
    if (tid == 0) scnt = 0;
    __syncthreads();
    const float4* row = (const float4*)(H + (size_t)bn * EE);
    for (int k = tid; k < EE / 4; k += 256) {
        float4 v = row[k];
        int mm = (v.x != 0.f) + (v.y != 0.f) + (v.z != 0.f) + (v.w != 0.f);
        if (mm) {                                  // ~3% of threads per iter
            int base = atomicAdd(&scnt, mm);       // LDS atomic only
            const int e0 = k * 4;
            if (v.x != 0.f) { if (base < MAXDEG) el[base] = e0;     base++; }
            if (v.y != 0.f) { if (base < MAXDEG) el[base] = e0 + 1; base++; }
            if (v.z != 0.f) { if (base < MAXDEG) el[base] = e0 + 2; base++; }
            if (v.w != 0.f) { if (base < MAXDEG) el[base] = e0 + 3; base++; }
        }
    }
    __syncthreads();
    const int cnt = scnt;
    const int m = min(cnt, MAXDEG);
    if (tid == 0) {
        rowcnt[bn] = cnt;                          // exact (dv exactness)
        dvinv[bn] = rsqrtf(fmaxf((float)cnt, EPSF));
    }
    if (tid < MAXDEG)                              // zero-filled tail
        csr16[(size_t)bn * MAXDEG + tid] = (tid < m) ? (unsigned short)el[tid] : 0;
    if (tid < m) {                                 // csc append (post-stream)
        const int q = (b << 12) + el[tid];
        const int slot = atomicAdd(&colcnt[q], 1);
        if (slot < MAXDEG) csc16[(size_t)q * MAXDEG + slot] = (unsigned short)nrel;
    }
    if (b == 0 && tid < HID) {                     // xw0, wave-0 lanes 0..31
        const int h = tid;
        const float* xr = X + (size_t)nrel * DIN;
        float acc = bi[h];
#pragma unroll 8
        for (int d = 0; d < DIN; d++) acc = fmaf(xr[d], Wi[d * HID + h], acc);
        sh[h] = fmaxf(acc, 0.f);                   // wave-internal
        float a = bn0[h];
#pragma unroll
        for (int k = 0; k < HID; k++) a = fmaf(sh[k], Wn0[k * HID + h], a);
        xw0[nrel * HID + h] = a;
    }
}

// ---------------------------------------------------------------------------
// K2 (x2): z[q,:] = de[q] * sum_{n in csc(q)} xw[n,:]*dvinv[b,n]
// ybuf never materialized. 8 loads batched before any accumulate (MLP).
// Poisoned tail slots load safe in-ws garbage; adds are masked by m.
// ---------------------------------------------------------------------------
__global__ __launch_bounds__(256) void k_z(
        const int* __restrict__ colcnt, const unsigned short* __restrict__ csc16,
        const float* __restrict__ xw, const float* __restrict__ dvinv,
        float* __restrict__ zbuf) {
    const int tid = threadIdx.x, h = tid & 31, g = tid >> 5;
    const int q = blockIdx.x * 8 + g;              // absolute edge row
    const int cnt = colcnt[q];
    const int m = min(cnt, MAXDEG);
    const int dvbase = q & ~(NN - 1);              // b*NN
    const unsigned int packed = ((const unsigned int*)csc16)[q * 32 + h];
    float acc[8] = {0.f, 0.f, 0.f, 0.f, 0.f, 0.f, 0.f, 0.f};
    for (int j0 = 0; j0 < m; j0 += 8) {
        float vs[8];
#pragma unroll
        for (int k = 0; k < 8; k++) {              // 16 independent loads
            const int j = j0 + k;
            const unsigned int p = __shfl(packed, j >> 1, 32);
            const int id = (j & 1) ? (int)(p >> 16) : (int)(p & 0xffffu);
            vs[k] = xw[id * HID + h] * dvinv[dvbase + id];
        }
#pragma unroll
        for (int k = 0; k < 8; k++) if (j0 + k < m) acc[k] += vs[k];
    }
    const float s = ((acc[0] + acc[1]) + (acc[2] + acc[3]))
                  + ((acc[4] + acc[5]) + (acc[6] + acc[7]));
    zbuf[(size_t)q * HID + h] = s * (1.0f / fmaxf((float)cnt, EPSF));
}

// ---------------------------------------------------------------------------
// One-hop gather over zbuf via csr16 (8-deep batched)
// ---------------------------------------------------------------------------
__device__ __forceinline__ float gatherz(const float* __restrict__ zb,
                                         unsigned int packed, int m, int h) {
    float acc[8] = {0.f, 0.f, 0.f, 0.f, 0.f, 0.f, 0.f, 0.f};
    for (int j0 = 0; j0 < m; j0 += 8) {
        float vs[8];
#pragma unroll
        for (int k = 0; k < 8; k++) {
            const int j = j0 + k;
            const unsigned int p = __shfl(packed, j >> 1, 32);
            const int id = (j & 1) ? (int)(p >> 16) : (int)(p & 0xffffu);
            vs[k] = zb[id * HID + h];
        }
#pragma unroll
        for (int k = 0; k < 8; k++) if (j0 + k < m) acc[k] += vs[k];
    }
    return ((acc[0] + acc[1]) + (acc[2] + acc[3]))
         + ((acc[4] + acc[5]) + (acc[6] + acc[7]));
}

__device__ __forceinline__ void softmax3(const float* __restrict__ bimp, float* sw) {
    float b0 = bimp[0], b1 = bimp[1], b2 = bimp[2];
    float mm = fmaxf(b0, fmaxf(b1, b2));
    float e0 = expf(b0 - mm), e1 = expf(b1 - mm), e2 = expf(b2 - mm);
    float s = e0 + e1 + e2;
    sw[0] = e0 / s; sw[1] = e1 / s; sw[2] = e2 / s;
}

// ---------------------------------------------------------------------------
// K3: layer-0 core -> x1; xw1 = x1@Wn1+bn1 (raw, dv applied inside k_z)
// ---------------------------------------------------------------------------
__global__ __launch_bounds__(256) void k_layer(
        const float* __restrict__ zbuf,
        const int* __restrict__ rowcnt, const unsigned short* __restrict__ csr16,
        const float* __restrict__ Theta, const float* __restrict__ bimp,
        const float* __restrict__ Wn1, const float* __restrict__ bn1,
        float* __restrict__ xw1) {
    __shared__ float sTh[BB * HID * HID];
    __shared__ float sW[HID * HID];
    __shared__ float sb[HID];
    __shared__ float su[8][HID];
    __shared__ float sw[4];
    const int tid = threadIdx.x;
    for (int i = tid; i < BB * HID * HID; i += 256) sTh[i] = Theta[i];
    for (int i = tid; i < HID * HID; i += 256) sW[i] = Wn1[i];
    if (tid < HID) sb[tid] = bn1[tid];
    if (tid == 0) softmax3(bimp, sw);
    __syncthreads();
    const int h = tid & 31, loc = tid >> 5;
    const int n = blockIdx.x * 8 + loc;
    float accx = 0.f;
#pragma unroll
    for (int b = 0; b < BB; b++) {
        const int r = (b << 12) + n;
        const int cnt = rowcnt[r];
        const int m = min(cnt, MAXDEG);
        const unsigned int packed = ((const unsigned int*)csr16)[r * 32 + h];
        const float u = gatherz(zbuf + (size_t)(b << 12) * HID, packed, m, h)
                        * rsqrtf(fmaxf((float)cnt, EPSF));
        su[loc][h] = u;                             // wave-internal
        float msg = 0.f;
#pragma unroll
        for (int hh = 0; hh < HID; hh++)
            msg = fmaf(su[loc][hh], sTh[b * (HID * HID) + hh * HID + h], msg);
        accx = fmaf(sw[b], msg, accx);
    }
    su[loc][h] = fmaxf(accx, 0.f);                  // x1
    float a = sb[h];
#pragma unroll
    for (int hh = 0; hh < HID; hh++) a = fmaf(su[loc][hh], sW[hh * HID + h], a);
    xw1[n * HID + h] = a;
}

// ---------------------------------------------------------------------------
// K4: layer-1 core -> x2; projection -> out
// ---------------------------------------------------------------------------
__global__ __launch_bounds__(256) void k_final(
        const float* __restrict__ zbuf,
        const int* __restrict__ rowcnt, const unsigned short* __restrict__ csr16,
        const float* __restrict__ Theta, const float* __restrict__ bimp,
        const float* __restrict__ Wp1, const float* __restrict__ bp1,
        const float* __restrict__ Wp2, const float* __restrict__ bp2,
        float* __restrict__ out) {
    __shared__ float sTh[BB * HID * HID];
    __shared__ float sW1[HID * HID], sW2[HID * HID];
    __shared__ float sb1[HID], sb2[HID];
    __shared__ float su[8][HID];
    __shared__ float sw[4];
    const int tid = threadIdx.x;
    for (int i = tid; i < BB * HID * HID; i += 256) sTh[i] = Theta[i];
    for (int i = tid; i < HID * HID; i += 256) { sW1[i] = Wp1[i]; sW2[i] = Wp2[i]; }
    if (tid < HID) { sb1[tid] = bp1[tid]; sb2[tid] = bp2[tid]; }
    if (tid == 0) softmax3(bimp, sw);
    __syncthreads();
    const int h = tid & 31, loc = tid >> 5;
    const int n = blockIdx.x * 8 + loc;
    float accx = 0.f;
#pragma unroll
    for (int b = 0; b < BB; b++) {
        const int r = (b << 12) + n;
        const int cnt = rowcnt[r];
        const int m = min(cnt, MAXDEG);
        const unsigned int packed = ((const unsigned int*)csr16)[r * 32 + h];
        const float u = gatherz(zbuf + (size_t)(b << 12) * HID, packed, m, h)
                        * rsqrtf(fmaxf((float)cnt, EPSF));
        su[loc][h] = u;
        float msg = 0.f;
#pragma unroll
        for (int hh = 0; hh < HID; hh++)
            msg = fmaf(su[loc][hh], sTh[b * (HID * HID) + hh * HID + h], msg);
        accx = fmaf(sw[b], msg, accx);
    }
    su[loc][h] = fmaxf(accx, 0.f);                  // x2
    float p = sb1[h];
#pragma unroll
    for (int hh = 0; hh < HID; hh++) p = fmaf(su[loc][hh], sW1[hh * HID + h], p);
    su[loc][h] = fmaxf(p, 0.f);                     // program-order within wave
    float o = sb2[h];
#pragma unroll
    for (int hh = 0; hh < HID; hh++) o = fmaf(su[loc][hh], sW2[hh * HID + h], o);
    out[(size_t)n * HID + h] = o;
}

// ---------------------------------------------------------------------------
extern "C" void kernel_launch(void* const* d_in, const int* in_sizes, int n_in,
                              void* d_out, int out_size, void* d_ws, size_t ws_size,
                              hipStream_t stream) {
    const float* X      = (const float*)d_in[0];
    const float* H      = (const float*)d_in[1];
    const float* W_init = (const float*)d_in[2];
    const float* b_init = (const float*)d_in[3];
    const float* W_node = (const float*)d_in[4];   // [2, HID, HID]
    const float* b_node = (const float*)d_in[5];   // [2, HID]
    const float* Theta  = (const float*)d_in[6];   // [BB, HID, HID]
    const float* bimp   = (const float*)d_in[7];   // [BB]
    const float* Wp1    = (const float*)d_in[8];
    const float* bp1    = (const float*)d_in[9];
    const float* Wp2    = (const float*)d_in[10];
    const float* bp2    = (const float*)d_in[11];
    float* out = (float*)d_out;
    (void)in_sizes; (void)n_in; (void)out_size; (void)ws_size;

    char* ws = (char*)d_ws;
    size_t off = 0;
    auto alloc = [&](size_t bytes) { void* p = ws + off; off += (bytes + 255) & ~(size_t)255; return p; };
    int*            rowcnt = (int*)alloc((size_t)BB * NN * 4);                 // 48 KB
    float*          dvinv  = (float*)alloc((size_t)BB * NN * 4);               // 48 KB
    int*            colcnt = (int*)alloc((size_t)BB * EE * 4);                 // 48 KB
    unsigned short* csr16  = (unsigned short*)alloc((size_t)BB * NN * MAXDEG * 2); // 1.5 MB
    unsigned short* csc16  = (unsigned short*)alloc((size_t)BB * EE * MAXDEG * 2); // 1.5 MB
    float*          xw0    = (float*)alloc((size_t)NN * HID * 4);              // 512 KB
    float*          xw1    = (float*)alloc((size_t)NN * HID * 4);              // 512 KB
    float*          zbuf   = (float*)alloc((size_t)BB * EE * HID * 4);         // 1.5 MB

    k_zero<<<(BB * EE + 255) / 256, 256, 0, stream>>>(colcnt, BB * EE);
    build_all<<<BB * NN, 256, 0, stream>>>(H, X, W_init, b_init, W_node, b_node,
                                           rowcnt, dvinv, colcnt, csr16, csc16, xw0);
    // layer 0
    k_z<<<(BB * EE) / 8, 256, 0, stream>>>(colcnt, csc16, xw0, dvinv, zbuf);
    k_layer<<<NN / 8, 256, 0, stream>>>(zbuf, rowcnt, csr16, Theta, bimp,
                                        W_node + HID * HID, b_node + HID, xw1);
    // layer 1 + projection (zbuf reused; kernel boundary orders RAW/WAR)
    k_z<<<(BB * EE) / 8, 256, 0, stream>>>(colcnt, csc16, xw1, dvinv, zbuf);
    k_final<<<NN / 8, 256, 0, stream>>>(zbuf, rowcnt, csr16, Theta, bimp,
                                        Wp1, bp1, Wp2, bp2, out);
}